// Round 1
// baseline (319.290 us; speedup 1.0000x reference)
//
#include <hip/hip_runtime.h>
#include <hip/hip_bf16.h>
#include <cstddef>

// FFTformer block. FFTs reduced to 8x8 circular convolutions; conv1x1 GEMMs
// on MFMA (bf16 in, fp32 acc), LN/gate fused into GEMM staging, weights
// pre-converted to padded bf16 (A-frags from global), vectorized epilogue via
// LDS transpose (16B stores). FSAS dwconv(q,k) fused into the patchconv.
// DFFN spectral filter = per-channel 64x64 circulant matmul on MFMA.
// B=2, d=48, H=W=256, P=8.  Workspace (ws_size = 256 MiB):
//   [0,           75,497,472)  QKV bf16 [2,288,HW]  (v + later y -> z in-place)
//   [75,497,472, 150,994,944)  HID bf16 [2,288,HW]
//   [150,994,944,176,160,768)  U   bf16 [2,96,HW]   (out96/u -> g1)
//   [176,160,768,188,743,680)  X1  bf16 [2,48,HW]
//   [188,743,680,201,326,592)  G2  bf16 [2,48,HW]   (CMAT 2.36MB until ffn_gate)
//   [201,326,592,201,424,896)  WPAD bf16 (awh64 | awo96 | fwi64 | fwo160)

constexpr int HWC = 65536;   // 256*256

typedef short short8 __attribute__((ext_vector_type(8)));
typedef __bf16 bf16x8 __attribute__((ext_vector_type(8)));
typedef float f32x4 __attribute__((ext_vector_type(4)));
typedef _Float16 f16x8 __attribute__((ext_vector_type(8)));

__device__ inline unsigned short f2bf(float f) {
  __hip_bfloat16 h = __float2bfloat16(f);
  return *reinterpret_cast<unsigned short*>(&h);
}
__device__ inline float bf2f(unsigned short u) {
  __hip_bfloat16 h;
  *reinterpret_cast<unsigned short*>(&h) = u;
  return __bfloat162float(h);
}

union V8 { uint4 v; unsigned short us[8]; short s[8]; };

__device__ inline void load8f(const unsigned short* p, float* f) {
  V8 u; u.v = *reinterpret_cast<const uint4*>(p);
#pragma unroll
  for (int j = 0; j < 8; j++) f[j] = bf2f(u.us[j]);
}
__device__ inline void store8bf(unsigned short* p, const float* f) {
  V8 u;
#pragma unroll
  for (int j = 0; j < 8; j++) u.us[j] = f2bf(f[j]);
  *reinterpret_cast<uint4*>(p) = u.v;
}

// ---------------------------------------------------------------------------
// Pre-convert weights fp32 -> bf16, zero-padded rows (offsets in shorts):
// awh [288][48]->@0 [288][64]; awo [48][96]->@18432; fwi [288][48]->@23040
// [288][64]; fwo [48][144]->@41472 [48][160].
__global__ __launch_bounds__(64) void k_prep_w(
    const float* __restrict__ awh, const float* __restrict__ awo,
    const float* __restrict__ fwi, const float* __restrict__ fwo,
    unsigned short* __restrict__ wp) {
  int row = blockIdx.x, t = threadIdx.x;
  const float* src; int K, KP; unsigned short* dst;
  if (row < 288)      { src = awh + row * 48;        K = 48;  KP = 64;
                        dst = wp + row * 64; }
  else if (row < 336) { int r = row - 288; src = awo + r * 96; K = 96; KP = 96;
                        dst = wp + 18432 + r * 96; }
  else if (row < 624) { int r = row - 336; src = fwi + r * 48; K = 48; KP = 64;
                        dst = wp + 23040 + r * 64; }
  else                { int r = row - 624; src = fwo + r * 144; K = 144; KP = 160;
                        dst = wp + 41472 + r * 160; }
  for (int k = t; k < KP; k += 64) dst[k] = f2bf(k < K ? src[k] : 0.f);
}

// ---------------------------------------------------------------------------
// MFMA GEMM: out[M x N] = Wb[M x KP(bf16)] * X[K x N], 64 px/block.
// XF: 0 none (K split 96/48 s1/s2), 1 LN48 fp32 s1, 2 LN96+v-gate, 3 LN48 bf16.
// EPI: 0 write bf16[M]; 1 += fp32 res -> bf16 (M=48); 2 += bf16 res -> fp32.
// Epilogue: accs -> LDS (reuse Xs) -> cooperative 16B stores.
template <int M, int K, int KP, int XF, int EPI>
__global__ __launch_bounds__(256) void k_gemm(
    const unsigned short* __restrict__ wb, const void* __restrict__ s1,
    const unsigned short* __restrict__ s2, const float* __restrict__ lnw,
    const float* __restrict__ lnb, const void* __restrict__ res,
    void* __restrict__ out) {
  constexpr int STRIDE = KP + 8;
  constexpr int KS = KP / 32;
  constexpr int NT = (M + 63) / 64;
  __shared__ __align__(16) short Xs[64 * STRIDE];   // staging, then epilogue
  __shared__ __align__(16) short Vs[(XF == 2) ? 64 * STRIDE : 4];
  __shared__ float redS[4][64], redS2[4][64], mus[64], invs[64];

  int tid = threadIdx.x;
  unsigned bid = blockIdx.x;
  int b = (int)(bid >> 10);
  int hw0 = (int)(bid & 1023) * 64;

  // stage X transposed: Xs[col][k]
  if (XF == 1) {
    const float* xp = (const float*)s1 + (size_t)b * 48 * HWC + hw0;
    for (int idx = tid; idx < 48 * 16; idx += 256) {
      int c = idx >> 4, colg = (idx & 15) * 4;
      float4 f = *reinterpret_cast<const float4*>(xp + (size_t)c * HWC + colg);
      Xs[(colg + 0) * STRIDE + c] = (short)f2bf(f.x);
      Xs[(colg + 1) * STRIDE + c] = (short)f2bf(f.y);
      Xs[(colg + 2) * STRIDE + c] = (short)f2bf(f.z);
      Xs[(colg + 3) * STRIDE + c] = (short)f2bf(f.w);
    }
  } else if (XF == 2) {
    const unsigned short* up =
        (const unsigned short*)s1 + (size_t)b * 96 * HWC + hw0;
    const unsigned short* vp = s2 + ((size_t)(b * 288 + 192)) * HWC + hw0;
    for (int idx = tid; idx < 96 * 16; idx += 256) {
      int c = idx >> 4, colg = (idx & 15) * 4;
      ushort4 uv = *reinterpret_cast<const ushort4*>(up + (size_t)c * HWC + colg);
      Xs[(colg + 0) * STRIDE + c] = (short)uv.x;
      Xs[(colg + 1) * STRIDE + c] = (short)uv.y;
      Xs[(colg + 2) * STRIDE + c] = (short)uv.z;
      Xs[(colg + 3) * STRIDE + c] = (short)uv.w;
      ushort4 vv = *reinterpret_cast<const ushort4*>(vp + (size_t)c * HWC + colg);
      Vs[(colg + 0) * STRIDE + c] = (short)vv.x;
      Vs[(colg + 1) * STRIDE + c] = (short)vv.y;
      Vs[(colg + 2) * STRIDE + c] = (short)vv.z;
      Vs[(colg + 3) * STRIDE + c] = (short)vv.w;
    }
  } else if (XF == 3) {
    const unsigned short* xp =
        (const unsigned short*)s1 + (size_t)b * 48 * HWC + hw0;
    for (int idx = tid; idx < 48 * 16; idx += 256) {
      int c = idx >> 4, colg = (idx & 15) * 4;
      ushort4 uv = *reinterpret_cast<const ushort4*>(xp + (size_t)c * HWC + colg);
      Xs[(colg + 0) * STRIDE + c] = (short)uv.x;
      Xs[(colg + 1) * STRIDE + c] = (short)uv.y;
      Xs[(colg + 2) * STRIDE + c] = (short)uv.z;
      Xs[(colg + 3) * STRIDE + c] = (short)uv.w;
    }
  } else {
    const unsigned short* p1 =
        (const unsigned short*)s1 + (size_t)b * 96 * HWC + hw0;
    const unsigned short* p2 = s2 + (size_t)b * 48 * HWC + hw0;
    for (int idx = tid; idx < K * 16; idx += 256) {
      int c = idx >> 4, colg = (idx & 15) * 4;
      const unsigned short* p =
          (c < 96) ? (p1 + (size_t)c * HWC + colg)
                   : (p2 + (size_t)(c - 96) * HWC + colg);
      ushort4 uv = *reinterpret_cast<const ushort4*>(p);
      Xs[(colg + 0) * STRIDE + c] = (short)uv.x;
      Xs[(colg + 1) * STRIDE + c] = (short)uv.y;
      Xs[(colg + 2) * STRIDE + c] = (short)uv.z;
      Xs[(colg + 3) * STRIDE + c] = (short)uv.w;
    }
  }

  if constexpr (KP > K) {
    constexpr int PAD = KP - K;
    for (int idx = tid; idx < 64 * PAD; idx += 256) {
      int col = idx / PAD, c = K + (idx % PAD);
      Xs[col * STRIDE + c] = 0;
    }
  }

  if (XF != 0) {
    constexpr int KC = (XF == 2) ? 96 : 48;
    __syncthreads();
    {
      int col = tid & 63, q = tid >> 6;
      float s = 0.f, s2 = 0.f;
      for (int c = q * (KC / 4); c < (q + 1) * (KC / 4); c++) {
        float v = bf2f((unsigned short)Xs[col * STRIDE + c]);
        s += v; s2 += v * v;
      }
      redS[q][col] = s; redS2[q][col] = s2;
    }
    __syncthreads();
    if (tid < 64) {
      float ss = redS[0][tid] + redS[1][tid] + redS[2][tid] + redS[3][tid];
      float ss2 = redS2[0][tid] + redS2[1][tid] + redS2[2][tid] + redS2[3][tid];
      float mu = ss * (1.f / KC);
      float var = ss2 * (1.f / KC) - mu * mu;
      mus[tid] = mu; invs[tid] = rsqrtf(var + 1e-5f);
    }
    __syncthreads();
    for (int idx = tid; idx < KC * 64; idx += 256) {
      int c = idx >> 6, col = idx & 63;
      float v = bf2f((unsigned short)Xs[col * STRIDE + c]);
      v = (v - mus[col]) * invs[col] * lnw[c] + lnb[c];
      if (XF == 2) v *= bf2f((unsigned short)Vs[col * STRIDE + c]);
      Xs[col * STRIDE + c] = (short)f2bf(v);
    }
  }
  __syncthreads();

  int lane = tid & 63, wvi = tid >> 6;
  int quad = lane >> 4, mc = lane & 15;
  int kbase = quad * 8;

  // B fragments to registers (Xs free for epilogue reuse afterwards)
  short8 bfr[4][KS];
#pragma unroll
  for (int ns = 0; ns < 4; ns++)
#pragma unroll
    for (int ks = 0; ks < KS; ks++)
      bfr[ns][ks] = *reinterpret_cast<const short8*>(
          Xs + (ns * 16 + mc) * STRIDE + ks * 32 + kbase);

  short* Es = Xs;   // epilogue tile [64ch][72]
#pragma unroll
  for (int t = 0; t < NT; t++) {
    int mb = (wvi + 4 * t) * 16;
    f32x4 accs[4];
    if (mb < M) {
      short8 afr[KS];
#pragma unroll
      for (int ks = 0; ks < KS; ks++)
        afr[ks] = *reinterpret_cast<const short8*>(
            wb + (size_t)(mb + mc) * KP + ks * 32 + kbase);
#pragma unroll
      for (int ns = 0; ns < 4; ns++) {
        f32x4 acc = {0.f, 0.f, 0.f, 0.f};
#pragma unroll
        for (int ks = 0; ks < KS; ks++)
          acc = __builtin_amdgcn_mfma_f32_16x16x32_bf16(
              __builtin_bit_cast(bf16x8, afr[ks]),
              __builtin_bit_cast(bf16x8, bfr[ns][ks]), acc, 0, 0, 0);
        accs[ns] = acc;
      }
    }
    __syncthreads();   // Xs free / previous writeback done
    if (mb < M) {
      int chl = wvi * 16 + quad * 4;
#pragma unroll
      for (int ns = 0; ns < 4; ns++)
#pragma unroll
        for (int r = 0; r < 4; r++)
          Es[(chl + r) * 72 + ns * 16 + mc] = (short)f2bf(accs[ns][r]);
    }
    __syncthreads();
#pragma unroll
    for (int i = 0; i < 2; i++) {
      int chl = (tid >> 3) + 32 * i;
      int px0 = (tid & 7) * 8;
      int m = 64 * t + chl;
      if (m < M) {
        V8 ev;
        ev.v = *reinterpret_cast<const uint4*>(Es + chl * 72 + px0);
        size_t off = ((size_t)(b * ((EPI == 0) ? M : 48) + m)) * HWC + hw0 + px0;
        if (EPI == 0) {
          *reinterpret_cast<uint4*>((unsigned short*)out + off) = ev.v;
        } else if (EPI == 1) {
          const float* rp = (const float*)res + off;
          float4 ra = *reinterpret_cast<const float4*>(rp);
          float4 rb = *reinterpret_cast<const float4*>(rp + 4);
          V8 pk;
          pk.us[0] = f2bf(ra.x + bf2f(ev.us[0]));
          pk.us[1] = f2bf(ra.y + bf2f(ev.us[1]));
          pk.us[2] = f2bf(ra.z + bf2f(ev.us[2]));
          pk.us[3] = f2bf(ra.w + bf2f(ev.us[3]));
          pk.us[4] = f2bf(rb.x + bf2f(ev.us[4]));
          pk.us[5] = f2bf(rb.y + bf2f(ev.us[5]));
          pk.us[6] = f2bf(rb.z + bf2f(ev.us[6]));
          pk.us[7] = f2bf(rb.w + bf2f(ev.us[7]));
          *reinterpret_cast<uint4*>((unsigned short*)out + off) = pk.v;
        } else {
          V8 rv;
          rv.v = *reinterpret_cast<const uint4*>((const unsigned short*)res + off);
          float* op = (float*)out + off;
          float4 oa, ob;
          oa.x = bf2f(rv.us[0]) + bf2f(ev.us[0]);
          oa.y = bf2f(rv.us[1]) + bf2f(ev.us[1]);
          oa.z = bf2f(rv.us[2]) + bf2f(ev.us[2]);
          oa.w = bf2f(rv.us[3]) + bf2f(ev.us[3]);
          ob.x = bf2f(rv.us[4]) + bf2f(ev.us[4]);
          ob.y = bf2f(rv.us[5]) + bf2f(ev.us[5]);
          ob.z = bf2f(rv.us[6]) + bf2f(ev.us[6]);
          ob.w = bf2f(rv.us[7]) + bf2f(ev.us[7]);
          *reinterpret_cast<float4*>(op) = oa;
          *reinterpret_cast<float4*>(op + 4) = ob;
        }
      }
    }
  }
}

// ---------------------------------------------------------------------------
// depthwise 3x3 SAME for the 96 v-channels (192..287), LDS-free.
__global__ __launch_bounds__(256) void k_dwconv3v(
    const unsigned short* __restrict__ in, const float* __restrict__ dw,
    unsigned short* __restrict__ out) {
  int tid = threadIdx.x;
  unsigned bid = blockIdx.x;
  int y0 = (int)(bid & 31) * 8;
  unsigned t = bid >> 5;
  int c = 192 + (int)(t % 96u);
  int b = (int)(t / 96u);
  const unsigned short* ip = in + ((size_t)(b * 288 + c)) * HWC;
  float wv[9];
#pragma unroll
  for (int k = 0; k < 9; k++) wv[k] = dw[c * 9 + k];
  int r = tid >> 5, seg = tid & 31, lane = tid & 63;
  int y = y0 + r;
  float f[3][8];
#pragma unroll
  for (int dy = 0; dy < 3; dy++) {
    int yy = y + dy - 1;
    if (yy >= 0 && yy < 256) {
      load8f(ip + yy * 256 + seg * 8, f[dy]);
    } else {
#pragma unroll
      for (int j = 0; j < 8; j++) f[dy][j] = 0.f;
    }
  }
  float o[8];
#pragma unroll
  for (int dy = 0; dy < 3; dy++) {
    float lv = __shfl(f[dy][7], lane - 1, 64);
    float rv = __shfl(f[dy][0], lane + 1, 64);
    if (seg == 0) lv = 0.f;
    if (seg == 31) rv = 0.f;
#pragma unroll
    for (int j = 0; j < 8; j++) {
      float xl = (j == 0) ? lv : f[dy][j - 1];
      float xr = (j == 7) ? rv : f[dy][j + 1];
      float v = xl * wv[dy * 3] + f[dy][j] * wv[dy * 3 + 1] + xr * wv[dy * 3 + 2];
      o[j] = (dy == 0) ? v : o[j] + v;
    }
  }
  store8bf(out + ((size_t)(b * 288 + c)) * HWC + y * 256 + seg * 8, o);
}

// ---------------------------------------------------------------------------
// FSAS fused: dwconv3(hidden) for q,k computed on the fly over a 64-row slab
// (shuffle halo; strips are full-width so halo is vertical only), staged to
// LDS as f16, then ONE THREAD PER 8x8 PATCH does the full circular
// convolution q (*) k in registers.  LDS reads are contiguous ds_read_b128
// (128 FMA per read vs 4 FMA per b32 read in the old row-per-thread scheme).
// Grid = 2*96*4 (quarter-image slabs), LDS 67.5 KB -> 2 blocks/CU.
__global__ __launch_bounds__(256) void k_fsas_fused(
    const unsigned short* __restrict__ hid, const float* __restrict__ dw,
    unsigned short* __restrict__ out) {
  constexpr int LSTR = 264;            // f16/row: 256 + 8 pad (16B aligned)
  __shared__ __align__(16) _Float16 qs[64 * LSTR];
  __shared__ __align__(16) _Float16 kt[64 * LSTR];
  int tid = threadIdx.x;
  unsigned bid = blockIdx.x;                 // b*96*4 + c*4 + qtr
  int qtr = (int)(bid & 3);
  int c = (int)((bid >> 2) % 96u);
  int b = (int)((bid >> 2) / 96u);
  int y0 = qtr * 64;
  const unsigned short* qp = hid + ((size_t)(b * 288 + c)) * HWC;
  const unsigned short* kp = hid + ((size_t)(b * 288 + 96 + c)) * HWC;
  float w1[9], w2[9];
#pragma unroll
  for (int k = 0; k < 9; k++) {
    w1[k] = dw[c * 9 + k];
    w2[k] = dw[(96 + c) * 9 + k];
  }
  int r = tid >> 5, seg = tid & 31, lane = tid & 63;
  // Phase 1: dwconv3 of q,k over 64 rows -> f16 LDS (8 strips of 8 rows)
  for (int s = 0; s < 8; s++) {
    int y = y0 + s * 8 + r;
    float f1[3][8], f2[3][8];
#pragma unroll
    for (int dy = 0; dy < 3; dy++) {
      int yy = y + dy - 1;
      if (yy >= 0 && yy < 256) {
        load8f(qp + yy * 256 + seg * 8, f1[dy]);
        load8f(kp + yy * 256 + seg * 8, f2[dy]);
      } else {
#pragma unroll
        for (int j = 0; j < 8; j++) { f1[dy][j] = 0.f; f2[dy][j] = 0.f; }
      }
    }
    float d1[8], d2[8];
#pragma unroll
    for (int j = 0; j < 8; j++) { d1[j] = 0.f; d2[j] = 0.f; }
#pragma unroll
    for (int dy = 0; dy < 3; dy++) {
      float lv1 = __shfl(f1[dy][7], lane - 1, 64);
      float rv1 = __shfl(f1[dy][0], lane + 1, 64);
      float lv2 = __shfl(f2[dy][7], lane - 1, 64);
      float rv2 = __shfl(f2[dy][0], lane + 1, 64);
      if (seg == 0) { lv1 = 0.f; lv2 = 0.f; }
      if (seg == 31) { rv1 = 0.f; rv2 = 0.f; }
#pragma unroll
      for (int j = 0; j < 8; j++) {
        float xl1 = (j == 0) ? lv1 : f1[dy][j - 1];
        float xr1 = (j == 7) ? rv1 : f1[dy][j + 1];
        float xl2 = (j == 0) ? lv2 : f2[dy][j - 1];
        float xr2 = (j == 7) ? rv2 : f2[dy][j + 1];
        d1[j] += xl1 * w1[dy * 3] + f1[dy][j] * w1[dy * 3 + 1] + xr1 * w1[dy * 3 + 2];
        d2[j] += xl2 * w2[dy * 3] + f2[dy][j] * w2[dy * 3 + 1] + xr2 * w2[dy * 3 + 2];
      }
    }
    f16x8 t1, t2;
#pragma unroll
    for (int j = 0; j < 8; j++) {
      t1[j] = (_Float16)d1[j];
      t2[j] = (_Float16)d2[j];
    }
    int row = s * 8 + r;
    *reinterpret_cast<f16x8*>(&qs[row * LSTR + seg * 8]) = t1;
    *reinterpret_cast<f16x8*>(&kt[row * LSTR + seg * 8]) = t2;
  }
  __syncthreads();
  // Phase 2: thread = patch (pr, pc). q fully in regs; k row per kr.
  int pr = tid >> 5, pc = tid & 31;
  const _Float16* qbase = &qs[(pr * 8) * LSTR + pc * 8];
  const _Float16* kbase = &kt[(pr * 8) * LSTR + pc * 8];
  float q[8][8];
#pragma unroll
  for (int i = 0; i < 8; i++) {
    f16x8 v = *reinterpret_cast<const f16x8*>(qbase + i * LSTR);
#pragma unroll
    for (int j = 0; j < 8; j++) q[i][j] = (float)v[j];
  }
  float acc[8][8];
#pragma unroll
  for (int a = 0; a < 8; a++)
#pragma unroll
    for (int bq = 0; bq < 8; bq++) acc[a][bq] = 0.f;
#pragma unroll
  for (int kr = 0; kr < 8; kr++) {
    f16x8 kv = *reinterpret_cast<const f16x8*>(kbase + kr * LSTR);
    float k8[8];
#pragma unroll
    for (int j = 0; j < 8; j++) k8[j] = (float)kv[j];
#pragma unroll
    for (int i = 0; i < 8; i++) {
      int o = (i + kr) & 7;
#pragma unroll
      for (int j = 0; j < 8; j++)
#pragma unroll
        for (int bq = 0; bq < 8; bq++)
          acc[o][bq] += q[i][j] * k8[(bq - j) & 7];
    }
  }
  unsigned short* op =
      out + ((size_t)(b * 96 + c)) * HWC + (y0 + pr * 8) * 256 + pc * 8;
#pragma unroll
  for (int a = 0; a < 8; a++) store8bf(op + a * 256, acc[a]);
}

// ---------------------------------------------------------------------------
// Cmat[c][m][k] (bf16): 64x64 circulant of s_c = irfft2(ffn_fft[c]) (numpy c2r
// semantics: v=0,4 columns symmetrized).
__device__ const float c_cos8[8] = {
    1.f, 0.70710678118654752f, 0.f, -0.70710678118654752f,
    -1.f, -0.70710678118654752f, 0.f, 0.70710678118654752f};

__global__ __launch_bounds__(64) void k_make_cmat(
    const float* __restrict__ fftw, unsigned short* __restrict__ cmat) {
  __shared__ float sf[64];
  int c = blockIdx.x;
  int a = threadIdx.x >> 3, b2 = threadIdx.x & 7;
  const float* W = fftw + c * 40;  // [8][5]
  float acc = 0.f;
  for (int u = 0; u < 8; u++) {
    for (int v = 0; v < 8; v++) {
      float wv;
      if (v <= 4) {
        if (v == 0 || v == 4)
          wv = 0.5f * (W[u * 5 + v] + W[((8 - u) & 7) * 5 + v]);
        else
          wv = W[u * 5 + v];
      } else {
        wv = W[((8 - u) & 7) * 5 + (8 - v)];
      }
      acc += wv * c_cos8[(u * a + v * b2) & 7];
    }
  }
  sf[threadIdx.x] = acc * (1.f / 64.f);
  __syncthreads();
  unsigned short* cp = cmat + (size_t)c * 4096 + threadIdx.x * 64;
  for (int k8 = 0; k8 < 64; k8 += 8) {
    float v[8];
    int ka = k8 >> 3;
    int ia = ((a - ka) & 7) * 8;
#pragma unroll
    for (int j = 0; j < 8; j++) v[j] = sf[ia + ((b2 - j) & 7)];
    store8bf(cp + k8, v);
  }
}

// ---------------------------------------------------------------------------
// DFFN spectral: z = C_c * y per patch, MFMA. IN-PLACE on y.
__global__ __launch_bounds__(256) void k_patchconv_mfma(
    unsigned short* y, const unsigned short* __restrict__ cmat) {
  __shared__ __align__(16) short Bs[32 * 72];
  __shared__ __align__(16) short As[64 * 72];
  int tid = threadIdx.x;
  unsigned bid = blockIdx.x;                 // b*288*32 + c*32 + py
  int py = (int)(bid & 31);
  int c = (int)((bid >> 5) % 288u);
  int b = (int)((bid >> 5) / 288u);
  unsigned short* yp = y + ((size_t)(b * 288 + c)) * HWC + py * 2048;
  {
    int rr = tid >> 5, seg = tid & 31;
    *reinterpret_cast<uint4*>(Bs + seg * 72 + rr * 8) =
        *reinterpret_cast<const uint4*>(yp + rr * 256 + seg * 8);
  }
  {
    const unsigned short* cp = cmat + (size_t)c * 4096;
    int m = tid >> 2, kq = (tid & 3) * 16;
    *reinterpret_cast<uint4*>(As + m * 72 + kq) =
        *reinterpret_cast<const uint4*>(cp + m * 64 + kq);
    *reinterpret_cast<uint4*>(As + m * 72 + kq + 8) =
        *reinterpret_cast<const uint4*>(cp + m * 64 + kq + 8);
  }
  __syncthreads();
  int lane = tid & 63, wvi = tid >> 6;
  int quad = lane >> 4, mc = lane & 15;
  int kbase = quad * 8;
  short8 afr[2];
#pragma unroll
  for (int ks = 0; ks < 2; ks++)
    afr[ks] = *reinterpret_cast<const short8*>(
        As + (wvi * 16 + mc) * 72 + ks * 32 + kbase);
#pragma unroll
  for (int nt = 0; nt < 2; nt++) {
    short8 bfr[2];
#pragma unroll
    for (int ks = 0; ks < 2; ks++)
      bfr[ks] = *reinterpret_cast<const short8*>(
          Bs + (nt * 16 + mc) * 72 + ks * 32 + kbase);
    f32x4 acc = {0.f, 0.f, 0.f, 0.f};
#pragma unroll
    for (int ks = 0; ks < 2; ks++)
      acc = __builtin_amdgcn_mfma_f32_16x16x32_bf16(
          __builtin_bit_cast(bf16x8, afr[ks]),
          __builtin_bit_cast(bf16x8, bfr[ks]), acc, 0, 0, 0);
    int p = nt * 16 + mc;
    int m0 = wvi * 16 + quad * 4;
    int a = m0 >> 3, b8 = m0 & 7;
    ushort4 pk;
    pk.x = f2bf(acc[0]); pk.y = f2bf(acc[1]);
    pk.z = f2bf(acc[2]); pk.w = f2bf(acc[3]);
    *reinterpret_cast<ushort4*>(yp + a * 256 + p * 8 + b8) = pk;
  }
}

// ---------------------------------------------------------------------------
// dwconv3 + exact GELU gate -> g bf16 (split g1[0:96) / g2[96:144)). LDS-free.
__global__ __launch_bounds__(256) void k_ffn_gate(
    const unsigned short* __restrict__ z, const float* __restrict__ dwf,
    unsigned short* __restrict__ g1, unsigned short* __restrict__ g2) {
  int tid = threadIdx.x;
  unsigned bid = blockIdx.x;
  int y0 = (int)(bid & 31) * 8;
  unsigned t = bid >> 5;
  int c = (int)(t % 144u);
  int b = (int)(t / 144u);
  const unsigned short* zp1 = z + ((size_t)(b * 288 + c)) * HWC;
  const unsigned short* zp2 = z + ((size_t)(b * 288 + 144 + c)) * HWC;
  float w1[9], w2[9];
#pragma unroll
  for (int k = 0; k < 9; k++) {
    w1[k] = dwf[c * 9 + k];
    w2[k] = dwf[(144 + c) * 9 + k];
  }
  int r = tid >> 5, seg = tid & 31, lane = tid & 63;
  int y = y0 + r;
  float f1[3][8], f2[3][8];
#pragma unroll
  for (int dy = 0; dy < 3; dy++) {
    int yy = y + dy - 1;
    if (yy >= 0 && yy < 256) {
      load8f(zp1 + yy * 256 + seg * 8, f1[dy]);
      load8f(zp2 + yy * 256 + seg * 8, f2[dy]);
    } else {
#pragma unroll
      for (int j = 0; j < 8; j++) { f1[dy][j] = 0.f; f2[dy][j] = 0.f; }
    }
  }
  float d1[8], d2[8];
#pragma unroll
  for (int j = 0; j < 8; j++) { d1[j] = 0.f; d2[j] = 0.f; }
#pragma unroll
  for (int dy = 0; dy < 3; dy++) {
    float lv1 = __shfl(f1[dy][7], lane - 1, 64);
    float rv1 = __shfl(f1[dy][0], lane + 1, 64);
    float lv2 = __shfl(f2[dy][7], lane - 1, 64);
    float rv2 = __shfl(f2[dy][0], lane + 1, 64);
    if (seg == 0) { lv1 = 0.f; lv2 = 0.f; }
    if (seg == 31) { rv1 = 0.f; rv2 = 0.f; }
#pragma unroll
    for (int j = 0; j < 8; j++) {
      float xl1 = (j == 0) ? lv1 : f1[dy][j - 1];
      float xr1 = (j == 7) ? rv1 : f1[dy][j + 1];
      float xl2 = (j == 0) ? lv2 : f2[dy][j - 1];
      float xr2 = (j == 7) ? rv2 : f2[dy][j + 1];
      d1[j] += xl1 * w1[dy * 3] + f1[dy][j] * w1[dy * 3 + 1] + xr1 * w1[dy * 3 + 2];
      d2[j] += xl2 * w2[dy * 3] + f2[dy][j] * w2[dy * 3 + 1] + xr2 * w2[dy * 3 + 2];
    }
  }
  float o[8];
#pragma unroll
  for (int j = 0; j < 8; j++)
    o[j] = 0.5f * d1[j] * (1.f + erff(d1[j] * 0.70710678118654752f)) * d2[j];
  unsigned short* gp = (c < 96)
      ? g1 + ((size_t)(b * 96 + c)) * HWC
      : g2 + ((size_t)(b * 48 + (c - 96))) * HWC;
  store8bf(gp + y * 256 + seg * 8, o);
}

// ---------------------------------------------------------------------------
extern "C" void kernel_launch(void* const* d_in, const int* in_sizes, int n_in,
                              void* d_out, int out_size, void* d_ws,
                              size_t ws_size, hipStream_t stream) {
  (void)in_sizes; (void)n_in; (void)out_size; (void)ws_size;
  const float* x   = (const float*)d_in[0];
  const float* n1w = (const float*)d_in[1];
  const float* n1b = (const float*)d_in[2];
  const float* awh = (const float*)d_in[3];   // [288,48]
  const float* adw = (const float*)d_in[4];   // [288,1,3,3]
  const float* anw = (const float*)d_in[5];   // [96]
  const float* anb = (const float*)d_in[6];
  const float* awo = (const float*)d_in[7];   // [48,96]
  const float* n2w = (const float*)d_in[8];
  const float* n2b = (const float*)d_in[9];
  const float* fwi = (const float*)d_in[10];  // [288,48]
  const float* fff = (const float*)d_in[11];  // [288,1,1,8,5]
  const float* fdw = (const float*)d_in[12];  // [288,1,3,3]
  const float* fwo = (const float*)d_in[13];  // [48,144]

  unsigned short* QKV  = (unsigned short*)d_ws;                       // 75.5 MB
  unsigned short* HID  = (unsigned short*)((char*)d_ws + 75497472);   // 75.5 MB
  unsigned short* U    = (unsigned short*)((char*)d_ws + 150994944);  // 25.2 MB
  unsigned short* X1   = (unsigned short*)((char*)d_ws + 176160768);  // 12.6 MB
  unsigned short* G2   = (unsigned short*)((char*)d_ws + 188743680);  // 12.6 MB
  unsigned short* CMAT = G2;  // 2.36 MB; dead before ffn_gate writes g2
  unsigned short* WP   = (unsigned short*)((char*)d_ws + 201326592);  // 96 KB
  unsigned short* WA = WP;             // awh padded [288][64]
  unsigned short* WO = WP + 18432;     // awo [48][96]
  unsigned short* WI = WP + 23040;     // fwi padded [288][64]
  unsigned short* WF = WP + 41472;     // fwo padded [48][160]

  k_prep_w<<<672, 64, 0, stream>>>(awh, awo, fwi, fwo, WP);
  k_make_cmat<<<288, 64, 0, stream>>>(fff, CMAT);
  // FSAS: hidden = W_h * LN1(x)  [LN fused]
  k_gemm<288, 48, 64, 1, 0><<<2048, 256, 0, stream>>>(WA, x, nullptr, n1w,
                                                      n1b, nullptr, HID);
  k_dwconv3v<<<2 * 96 * 32, 256, 0, stream>>>(HID, adw, QKV);      // v only
  k_fsas_fused<<<2 * 96 * 4, 256, 0, stream>>>(HID, adw, U);       // q,k fused
  // x1 = x + W_o * (LN(out96) * v)   [LN+gate fused in staging]
  k_gemm<48, 96, 96, 2, 1><<<2048, 256, 0, stream>>>(WO, U, QKV, anw, anb, x,
                                                     X1);
  // DFFN: y = W_in * LN(x1)  [LN fused]
  k_gemm<288, 48, 64, 3, 0><<<2048, 256, 0, stream>>>(WI, X1, nullptr, n2w,
                                                      n2b, nullptr, QKV);
  // z = C_c * y per patch (MFMA circulant), in-place
  k_patchconv_mfma<<<2 * 288 * 32, 256, 0, stream>>>(QKV, CMAT);
  k_ffn_gate<<<2 * 144 * 32, 256, 0, stream>>>(QKV, fdw, U, G2);
  // out = x1 + W_out * g  (g split U/G2), fp32 output
  k_gemm<48, 144, 160, 0, 2><<<2048, 256, 0, stream>>>(WF, U, G2, nullptr,
                                                       nullptr, X1,
                                                       (float*)d_out);
}

// Round 2
// 292.790 us; speedup vs baseline: 1.0905x; 1.0905x over previous
//
#include <hip/hip_runtime.h>
#include <hip/hip_bf16.h>
#include <cstddef>

// FFTformer block. FFTs reduced to 8x8 circular convolutions; conv1x1 GEMMs
// on MFMA (bf16 in, fp32 acc), LN/gate fused into GEMM staging, weights
// pre-converted to padded bf16 (A-frags from global), vectorized epilogue via
// LDS transpose (16B stores). FSAS dwconv(q,k) fused into the patchconv.
// DFFN spectral filter = per-channel 64x64 circulant matmul on MFMA.
// B=2, d=48, H=W=256, P=8.  Workspace (ws_size = 256 MiB):
//   [0,           75,497,472)  QKV bf16 [2,288,HW]  (v + later y -> z in-place)
//   [75,497,472, 150,994,944)  HID bf16 [2,288,HW]
//   [150,994,944,176,160,768)  U   bf16 [2,96,HW]   (out96/u -> g1)
//   [176,160,768,188,743,680)  X1  bf16 [2,48,HW]
//   [188,743,680,201,326,592)  G2  bf16 [2,48,HW]   (CMAT 2.36MB until ffn_gate)
//   [201,326,592,201,424,896)  WPAD bf16 (awh64 | awo96 | fwi64 | fwo160)

constexpr int HWC = 65536;   // 256*256

typedef short short8 __attribute__((ext_vector_type(8)));
typedef __bf16 bf16x8 __attribute__((ext_vector_type(8)));
typedef float f32x4 __attribute__((ext_vector_type(4)));

__device__ inline unsigned short f2bf(float f) {
  __hip_bfloat16 h = __float2bfloat16(f);
  return *reinterpret_cast<unsigned short*>(&h);
}
__device__ inline float bf2f(unsigned short u) {
  __hip_bfloat16 h;
  *reinterpret_cast<unsigned short*>(&h) = u;
  return __bfloat162float(h);
}

union V8 { uint4 v; unsigned short us[8]; short s[8]; };

__device__ inline void load8f(const unsigned short* p, float* f) {
  V8 u; u.v = *reinterpret_cast<const uint4*>(p);
#pragma unroll
  for (int j = 0; j < 8; j++) f[j] = bf2f(u.us[j]);
}
__device__ inline void store8bf(unsigned short* p, const float* f) {
  V8 u;
#pragma unroll
  for (int j = 0; j < 8; j++) u.us[j] = f2bf(f[j]);
  *reinterpret_cast<uint4*>(p) = u.v;
}

// ---------------------------------------------------------------------------
// Pre-convert weights fp32 -> bf16, zero-padded rows (offsets in shorts):
// awh [288][48]->@0 [288][64]; awo [48][96]->@18432; fwi [288][48]->@23040
// [288][64]; fwo [48][144]->@41472 [48][160].
__global__ __launch_bounds__(64) void k_prep_w(
    const float* __restrict__ awh, const float* __restrict__ awo,
    const float* __restrict__ fwi, const float* __restrict__ fwo,
    unsigned short* __restrict__ wp) {
  int row = blockIdx.x, t = threadIdx.x;
  const float* src; int K, KP; unsigned short* dst;
  if (row < 288)      { src = awh + row * 48;        K = 48;  KP = 64;
                        dst = wp + row * 64; }
  else if (row < 336) { int r = row - 288; src = awo + r * 96; K = 96; KP = 96;
                        dst = wp + 18432 + r * 96; }
  else if (row < 624) { int r = row - 336; src = fwi + r * 48; K = 48; KP = 64;
                        dst = wp + 23040 + r * 64; }
  else                { int r = row - 624; src = fwo + r * 144; K = 144; KP = 160;
                        dst = wp + 41472 + r * 160; }
  for (int k = t; k < KP; k += 64) dst[k] = f2bf(k < K ? src[k] : 0.f);
}

// ---------------------------------------------------------------------------
// MFMA GEMM: out[M x N] = Wb[M x KP(bf16)] * X[K x N], 64 px/block.
// XF: 0 none (K split 96/48 s1/s2), 1 LN48 fp32 s1, 2 LN96+v-gate, 3 LN48 bf16.
// EPI: 0 write bf16[M]; 1 += fp32 res -> bf16 (M=48); 2 += bf16 res -> fp32.
// Epilogue: accs -> LDS (reuse Xs) -> cooperative 16B stores.
template <int M, int K, int KP, int XF, int EPI>
__global__ __launch_bounds__(256) void k_gemm(
    const unsigned short* __restrict__ wb, const void* __restrict__ s1,
    const unsigned short* __restrict__ s2, const float* __restrict__ lnw,
    const float* __restrict__ lnb, const void* __restrict__ res,
    void* __restrict__ out) {
  constexpr int STRIDE = KP + 8;
  constexpr int KS = KP / 32;
  constexpr int NT = (M + 63) / 64;
  __shared__ __align__(16) short Xs[64 * STRIDE];   // staging, then epilogue
  __shared__ __align__(16) short Vs[(XF == 2) ? 64 * STRIDE : 4];
  __shared__ float redS[4][64], redS2[4][64], mus[64], invs[64];

  int tid = threadIdx.x;
  unsigned bid = blockIdx.x;
  int b = (int)(bid >> 10);
  int hw0 = (int)(bid & 1023) * 64;

  // stage X transposed: Xs[col][k]
  if (XF == 1) {
    const float* xp = (const float*)s1 + (size_t)b * 48 * HWC + hw0;
    for (int idx = tid; idx < 48 * 16; idx += 256) {
      int c = idx >> 4, colg = (idx & 15) * 4;
      float4 f = *reinterpret_cast<const float4*>(xp + (size_t)c * HWC + colg);
      Xs[(colg + 0) * STRIDE + c] = (short)f2bf(f.x);
      Xs[(colg + 1) * STRIDE + c] = (short)f2bf(f.y);
      Xs[(colg + 2) * STRIDE + c] = (short)f2bf(f.z);
      Xs[(colg + 3) * STRIDE + c] = (short)f2bf(f.w);
    }
  } else if (XF == 2) {
    const unsigned short* up =
        (const unsigned short*)s1 + (size_t)b * 96 * HWC + hw0;
    const unsigned short* vp = s2 + ((size_t)(b * 288 + 192)) * HWC + hw0;
    for (int idx = tid; idx < 96 * 16; idx += 256) {
      int c = idx >> 4, colg = (idx & 15) * 4;
      ushort4 uv = *reinterpret_cast<const ushort4*>(up + (size_t)c * HWC + colg);
      Xs[(colg + 0) * STRIDE + c] = (short)uv.x;
      Xs[(colg + 1) * STRIDE + c] = (short)uv.y;
      Xs[(colg + 2) * STRIDE + c] = (short)uv.z;
      Xs[(colg + 3) * STRIDE + c] = (short)uv.w;
      ushort4 vv = *reinterpret_cast<const ushort4*>(vp + (size_t)c * HWC + colg);
      Vs[(colg + 0) * STRIDE + c] = (short)vv.x;
      Vs[(colg + 1) * STRIDE + c] = (short)vv.y;
      Vs[(colg + 2) * STRIDE + c] = (short)vv.z;
      Vs[(colg + 3) * STRIDE + c] = (short)vv.w;
    }
  } else if (XF == 3) {
    const unsigned short* xp =
        (const unsigned short*)s1 + (size_t)b * 48 * HWC + hw0;
    for (int idx = tid; idx < 48 * 16; idx += 256) {
      int c = idx >> 4, colg = (idx & 15) * 4;
      ushort4 uv = *reinterpret_cast<const ushort4*>(xp + (size_t)c * HWC + colg);
      Xs[(colg + 0) * STRIDE + c] = (short)uv.x;
      Xs[(colg + 1) * STRIDE + c] = (short)uv.y;
      Xs[(colg + 2) * STRIDE + c] = (short)uv.z;
      Xs[(colg + 3) * STRIDE + c] = (short)uv.w;
    }
  } else {
    const unsigned short* p1 =
        (const unsigned short*)s1 + (size_t)b * 96 * HWC + hw0;
    const unsigned short* p2 = s2 + (size_t)b * 48 * HWC + hw0;
    for (int idx = tid; idx < K * 16; idx += 256) {
      int c = idx >> 4, colg = (idx & 15) * 4;
      const unsigned short* p =
          (c < 96) ? (p1 + (size_t)c * HWC + colg)
                   : (p2 + (size_t)(c - 96) * HWC + colg);
      ushort4 uv = *reinterpret_cast<const ushort4*>(p);
      Xs[(colg + 0) * STRIDE + c] = (short)uv.x;
      Xs[(colg + 1) * STRIDE + c] = (short)uv.y;
      Xs[(colg + 2) * STRIDE + c] = (short)uv.z;
      Xs[(colg + 3) * STRIDE + c] = (short)uv.w;
    }
  }

  if constexpr (KP > K) {
    constexpr int PAD = KP - K;
    for (int idx = tid; idx < 64 * PAD; idx += 256) {
      int col = idx / PAD, c = K + (idx % PAD);
      Xs[col * STRIDE + c] = 0;
    }
  }

  if (XF != 0) {
    constexpr int KC = (XF == 2) ? 96 : 48;
    __syncthreads();
    {
      int col = tid & 63, q = tid >> 6;
      float s = 0.f, s2 = 0.f;
      for (int c = q * (KC / 4); c < (q + 1) * (KC / 4); c++) {
        float v = bf2f((unsigned short)Xs[col * STRIDE + c]);
        s += v; s2 += v * v;
      }
      redS[q][col] = s; redS2[q][col] = s2;
    }
    __syncthreads();
    if (tid < 64) {
      float ss = redS[0][tid] + redS[1][tid] + redS[2][tid] + redS[3][tid];
      float ss2 = redS2[0][tid] + redS2[1][tid] + redS2[2][tid] + redS2[3][tid];
      float mu = ss * (1.f / KC);
      float var = ss2 * (1.f / KC) - mu * mu;
      mus[tid] = mu; invs[tid] = rsqrtf(var + 1e-5f);
    }
    __syncthreads();
    for (int idx = tid; idx < KC * 64; idx += 256) {
      int c = idx >> 6, col = idx & 63;
      float v = bf2f((unsigned short)Xs[col * STRIDE + c]);
      v = (v - mus[col]) * invs[col] * lnw[c] + lnb[c];
      if (XF == 2) v *= bf2f((unsigned short)Vs[col * STRIDE + c]);
      Xs[col * STRIDE + c] = (short)f2bf(v);
    }
  }
  __syncthreads();

  int lane = tid & 63, wvi = tid >> 6;
  int quad = lane >> 4, mc = lane & 15;
  int kbase = quad * 8;

  // B fragments to registers (Xs free for epilogue reuse afterwards)
  short8 bfr[4][KS];
#pragma unroll
  for (int ns = 0; ns < 4; ns++)
#pragma unroll
    for (int ks = 0; ks < KS; ks++)
      bfr[ns][ks] = *reinterpret_cast<const short8*>(
          Xs + (ns * 16 + mc) * STRIDE + ks * 32 + kbase);

  short* Es = Xs;   // epilogue tile [64ch][72]
#pragma unroll
  for (int t = 0; t < NT; t++) {
    int mb = (wvi + 4 * t) * 16;
    f32x4 accs[4];
    if (mb < M) {
      short8 afr[KS];
#pragma unroll
      for (int ks = 0; ks < KS; ks++)
        afr[ks] = *reinterpret_cast<const short8*>(
            wb + (size_t)(mb + mc) * KP + ks * 32 + kbase);
#pragma unroll
      for (int ns = 0; ns < 4; ns++) {
        f32x4 acc = {0.f, 0.f, 0.f, 0.f};
#pragma unroll
        for (int ks = 0; ks < KS; ks++)
          acc = __builtin_amdgcn_mfma_f32_16x16x32_bf16(
              __builtin_bit_cast(bf16x8, afr[ks]),
              __builtin_bit_cast(bf16x8, bfr[ns][ks]), acc, 0, 0, 0);
        accs[ns] = acc;
      }
    }
    __syncthreads();   // Xs free / previous writeback done
    if (mb < M) {
      int chl = wvi * 16 + quad * 4;
#pragma unroll
      for (int ns = 0; ns < 4; ns++)
#pragma unroll
        for (int r = 0; r < 4; r++)
          Es[(chl + r) * 72 + ns * 16 + mc] = (short)f2bf(accs[ns][r]);
    }
    __syncthreads();
#pragma unroll
    for (int i = 0; i < 2; i++) {
      int chl = (tid >> 3) + 32 * i;
      int px0 = (tid & 7) * 8;
      int m = 64 * t + chl;
      if (m < M) {
        V8 ev;
        ev.v = *reinterpret_cast<const uint4*>(Es + chl * 72 + px0);
        size_t off = ((size_t)(b * ((EPI == 0) ? M : 48) + m)) * HWC + hw0 + px0;
        if (EPI == 0) {
          *reinterpret_cast<uint4*>((unsigned short*)out + off) = ev.v;
        } else if (EPI == 1) {
          const float* rp = (const float*)res + off;
          float4 ra = *reinterpret_cast<const float4*>(rp);
          float4 rb = *reinterpret_cast<const float4*>(rp + 4);
          V8 pk;
          pk.us[0] = f2bf(ra.x + bf2f(ev.us[0]));
          pk.us[1] = f2bf(ra.y + bf2f(ev.us[1]));
          pk.us[2] = f2bf(ra.z + bf2f(ev.us[2]));
          pk.us[3] = f2bf(ra.w + bf2f(ev.us[3]));
          pk.us[4] = f2bf(rb.x + bf2f(ev.us[4]));
          pk.us[5] = f2bf(rb.y + bf2f(ev.us[5]));
          pk.us[6] = f2bf(rb.z + bf2f(ev.us[6]));
          pk.us[7] = f2bf(rb.w + bf2f(ev.us[7]));
          *reinterpret_cast<uint4*>((unsigned short*)out + off) = pk.v;
        } else {
          V8 rv;
          rv.v = *reinterpret_cast<const uint4*>((const unsigned short*)res + off);
          float* op = (float*)out + off;
          float4 oa, ob;
          oa.x = bf2f(rv.us[0]) + bf2f(ev.us[0]);
          oa.y = bf2f(rv.us[1]) + bf2f(ev.us[1]);
          oa.z = bf2f(rv.us[2]) + bf2f(ev.us[2]);
          oa.w = bf2f(rv.us[3]) + bf2f(ev.us[3]);
          ob.x = bf2f(rv.us[4]) + bf2f(ev.us[4]);
          ob.y = bf2f(rv.us[5]) + bf2f(ev.us[5]);
          ob.z = bf2f(rv.us[6]) + bf2f(ev.us[6]);
          ob.w = bf2f(rv.us[7]) + bf2f(ev.us[7]);
          *reinterpret_cast<float4*>(op) = oa;
          *reinterpret_cast<float4*>(op + 4) = ob;
        }
      }
    }
  }
}

// ---------------------------------------------------------------------------
// depthwise 3x3 SAME for the 96 v-channels (192..287), LDS-free.
__global__ __launch_bounds__(256) void k_dwconv3v(
    const unsigned short* __restrict__ in, const float* __restrict__ dw,
    unsigned short* __restrict__ out) {
  int tid = threadIdx.x;
  unsigned bid = blockIdx.x;
  int y0 = (int)(bid & 31) * 8;
  unsigned t = bid >> 5;
  int c = 192 + (int)(t % 96u);
  int b = (int)(t / 96u);
  const unsigned short* ip = in + ((size_t)(b * 288 + c)) * HWC;
  float wv[9];
#pragma unroll
  for (int k = 0; k < 9; k++) wv[k] = dw[c * 9 + k];
  int r = tid >> 5, seg = tid & 31, lane = tid & 63;
  int y = y0 + r;
  float f[3][8];
#pragma unroll
  for (int dy = 0; dy < 3; dy++) {
    int yy = y + dy - 1;
    if (yy >= 0 && yy < 256) {
      load8f(ip + yy * 256 + seg * 8, f[dy]);
    } else {
#pragma unroll
      for (int j = 0; j < 8; j++) f[dy][j] = 0.f;
    }
  }
  float o[8];
#pragma unroll
  for (int dy = 0; dy < 3; dy++) {
    float lv = __shfl(f[dy][7], lane - 1, 64);
    float rv = __shfl(f[dy][0], lane + 1, 64);
    if (seg == 0) lv = 0.f;
    if (seg == 31) rv = 0.f;
#pragma unroll
    for (int j = 0; j < 8; j++) {
      float xl = (j == 0) ? lv : f[dy][j - 1];
      float xr = (j == 7) ? rv : f[dy][j + 1];
      float v = xl * wv[dy * 3] + f[dy][j] * wv[dy * 3 + 1] + xr * wv[dy * 3 + 2];
      o[j] = (dy == 0) ? v : o[j] + v;
    }
  }
  store8bf(out + ((size_t)(b * 288 + c)) * HWC + y * 256 + seg * 8, o);
}

// ---------------------------------------------------------------------------
// FSAS fused: dwconv3(hidden) for q,k computed on the fly (shuffle halo,
// strips are full-width so halo is vertical only), then per-patch 8x8
// circular convolution q (*) k.  LDS layout: row-contiguous f32, LSTR=260
// (16B-aligned rows, +4 bank shift/row).  Phase 2: q-row reads are 8-lane
// same-address broadcasts (free); k-row reads land 8 dwords/bank (even).
// 32 x ds_read_b128 per thread replaces 128 scalar b32 of the stride-9 layout.
__global__ __launch_bounds__(256) void k_fsas_fused(
    const unsigned short* __restrict__ hid, const float* __restrict__ dw,
    unsigned short* __restrict__ out) {
  constexpr int LSTR = 260;            // f32/row: 256 + 4 pad
  __shared__ __align__(16) float qs[8 * LSTR];
  __shared__ __align__(16) float kt[8 * LSTR];
  int tid = threadIdx.x;
  unsigned bid = blockIdx.x;                 // b*96*32 + c*32 + py
  int py = (int)(bid & 31);
  int c = (int)((bid >> 5) % 96u);
  int b = (int)((bid >> 5) / 96u);
  const unsigned short* qp = hid + ((size_t)(b * 288 + c)) * HWC;
  const unsigned short* kp = hid + ((size_t)(b * 288 + 96 + c)) * HWC;
  float w1[9], w2[9];
#pragma unroll
  for (int k = 0; k < 9; k++) {
    w1[k] = dw[c * 9 + k];
    w2[k] = dw[(96 + c) * 9 + k];
  }
  int r = tid >> 5, seg = tid & 31, lane = tid & 63;
  int y = py * 8 + r;
  float f1[3][8], f2[3][8];
#pragma unroll
  for (int dy = 0; dy < 3; dy++) {
    int yy = y + dy - 1;
    if (yy >= 0 && yy < 256) {
      load8f(qp + yy * 256 + seg * 8, f1[dy]);
      load8f(kp + yy * 256 + seg * 8, f2[dy]);
    } else {
#pragma unroll
      for (int j = 0; j < 8; j++) { f1[dy][j] = 0.f; f2[dy][j] = 0.f; }
    }
  }
  float d1[8], d2[8];
#pragma unroll
  for (int j = 0; j < 8; j++) { d1[j] = 0.f; d2[j] = 0.f; }
#pragma unroll
  for (int dy = 0; dy < 3; dy++) {
    float lv1 = __shfl(f1[dy][7], lane - 1, 64);
    float rv1 = __shfl(f1[dy][0], lane + 1, 64);
    float lv2 = __shfl(f2[dy][7], lane - 1, 64);
    float rv2 = __shfl(f2[dy][0], lane + 1, 64);
    if (seg == 0) { lv1 = 0.f; lv2 = 0.f; }
    if (seg == 31) { rv1 = 0.f; rv2 = 0.f; }
#pragma unroll
    for (int j = 0; j < 8; j++) {
      float xl1 = (j == 0) ? lv1 : f1[dy][j - 1];
      float xr1 = (j == 7) ? rv1 : f1[dy][j + 1];
      float xl2 = (j == 0) ? lv2 : f2[dy][j - 1];
      float xr2 = (j == 7) ? rv2 : f2[dy][j + 1];
      d1[j] += xl1 * w1[dy * 3] + f1[dy][j] * w1[dy * 3 + 1] + xr1 * w1[dy * 3 + 2];
      d2[j] += xl2 * w2[dy * 3] + f2[dy][j] * w2[dy * 3 + 1] + xr2 * w2[dy * 3 + 2];
    }
  }
  {
    float4 a1 = {d1[0], d1[1], d1[2], d1[3]};
    float4 b1 = {d1[4], d1[5], d1[6], d1[7]};
    float4 a2 = {d2[0], d2[1], d2[2], d2[3]};
    float4 b2 = {d2[4], d2[5], d2[6], d2[7]};
    *reinterpret_cast<float4*>(&qs[r * LSTR + seg * 8]) = a1;
    *reinterpret_cast<float4*>(&qs[r * LSTR + seg * 8 + 4]) = b1;
    *reinterpret_cast<float4*>(&kt[r * LSTR + seg * 8]) = a2;
    *reinterpret_cast<float4*>(&kt[r * LSTR + seg * 8 + 4]) = b2;
  }
  __syncthreads();
  // Phase 2: patch p = tid>>3 (col), output row a = tid&7.
  int p = tid >> 3, a = tid & 7;
  float acc[8];
#pragma unroll
  for (int j = 0; j < 8; j++) acc[j] = 0.f;
#pragma unroll
  for (int i = 0; i < 8; i++) {
    float4 qa = *reinterpret_cast<const float4*>(&qs[i * LSTR + p * 8]);
    float4 qb = *reinterpret_cast<const float4*>(&qs[i * LSTR + p * 8 + 4]);
    float q8[8] = {qa.x, qa.y, qa.z, qa.w, qb.x, qb.y, qb.z, qb.w};
    int ar = (a - i) & 7;
    float4 ka = *reinterpret_cast<const float4*>(&kt[ar * LSTR + p * 8]);
    float4 kb = *reinterpret_cast<const float4*>(&kt[ar * LSTR + p * 8 + 4]);
    float k8[8] = {ka.x, ka.y, ka.z, ka.w, kb.x, kb.y, kb.z, kb.w};
#pragma unroll
    for (int j = 0; j < 8; j++)
#pragma unroll
      for (int bb = 0; bb < 8; bb++) acc[bb] += q8[j] * k8[(bb - j) & 7];
  }
  store8bf(out + ((size_t)(b * 96 + c)) * HWC + (py * 8 + a) * 256 + p * 8,
           acc);
}

// ---------------------------------------------------------------------------
// Cmat[c][m][k] (bf16): 64x64 circulant of s_c = irfft2(ffn_fft[c]) (numpy c2r
// semantics: v=0,4 columns symmetrized).
__device__ const float c_cos8[8] = {
    1.f, 0.70710678118654752f, 0.f, -0.70710678118654752f,
    -1.f, -0.70710678118654752f, 0.f, 0.70710678118654752f};

__global__ __launch_bounds__(64) void k_make_cmat(
    const float* __restrict__ fftw, unsigned short* __restrict__ cmat) {
  __shared__ float sf[64];
  int c = blockIdx.x;
  int a = threadIdx.x >> 3, b2 = threadIdx.x & 7;
  const float* W = fftw + c * 40;  // [8][5]
  float acc = 0.f;
  for (int u = 0; u < 8; u++) {
    for (int v = 0; v < 8; v++) {
      float wv;
      if (v <= 4) {
        if (v == 0 || v == 4)
          wv = 0.5f * (W[u * 5 + v] + W[((8 - u) & 7) * 5 + v]);
        else
          wv = W[u * 5 + v];
      } else {
        wv = W[((8 - u) & 7) * 5 + (8 - v)];
      }
      acc += wv * c_cos8[(u * a + v * b2) & 7];
    }
  }
  sf[threadIdx.x] = acc * (1.f / 64.f);
  __syncthreads();
  unsigned short* cp = cmat + (size_t)c * 4096 + threadIdx.x * 64;
  for (int k8 = 0; k8 < 64; k8 += 8) {
    float v[8];
    int ka = k8 >> 3;
    int ia = ((a - ka) & 7) * 8;
#pragma unroll
    for (int j = 0; j < 8; j++) v[j] = sf[ia + ((b2 - j) & 7)];
    store8bf(cp + k8, v);
  }
}

// ---------------------------------------------------------------------------
// DFFN spectral: z = C_c * y per patch, MFMA. IN-PLACE on y.
__global__ __launch_bounds__(256) void k_patchconv_mfma(
    unsigned short* y, const unsigned short* __restrict__ cmat) {
  __shared__ __align__(16) short Bs[32 * 72];
  __shared__ __align__(16) short As[64 * 72];
  int tid = threadIdx.x;
  unsigned bid = blockIdx.x;                 // b*288*32 + c*32 + py
  int py = (int)(bid & 31);
  int c = (int)((bid >> 5) % 288u);
  int b = (int)((bid >> 5) / 288u);
  unsigned short* yp = y + ((size_t)(b * 288 + c)) * HWC + py * 2048;
  {
    int rr = tid >> 5, seg = tid & 31;
    *reinterpret_cast<uint4*>(Bs + seg * 72 + rr * 8) =
        *reinterpret_cast<const uint4*>(yp + rr * 256 + seg * 8);
  }
  {
    const unsigned short* cp = cmat + (size_t)c * 4096;
    int m = tid >> 2, kq = (tid & 3) * 16;
    *reinterpret_cast<uint4*>(As + m * 72 + kq) =
        *reinterpret_cast<const uint4*>(cp + m * 64 + kq);
    *reinterpret_cast<uint4*>(As + m * 72 + kq + 8) =
        *reinterpret_cast<const uint4*>(cp + m * 64 + kq + 8);
  }
  __syncthreads();
  int lane = tid & 63, wvi = tid >> 6;
  int quad = lane >> 4, mc = lane & 15;
  int kbase = quad * 8;
  short8 afr[2];
#pragma unroll
  for (int ks = 0; ks < 2; ks++)
    afr[ks] = *reinterpret_cast<const short8*>(
        As + (wvi * 16 + mc) * 72 + ks * 32 + kbase);
#pragma unroll
  for (int nt = 0; nt < 2; nt++) {
    short8 bfr[2];
#pragma unroll
    for (int ks = 0; ks < 2; ks++)
      bfr[ks] = *reinterpret_cast<const short8*>(
          Bs + (nt * 16 + mc) * 72 + ks * 32 + kbase);
    f32x4 acc = {0.f, 0.f, 0.f, 0.f};
#pragma unroll
    for (int ks = 0; ks < 2; ks++)
      acc = __builtin_amdgcn_mfma_f32_16x16x32_bf16(
          __builtin_bit_cast(bf16x8, afr[ks]),
          __builtin_bit_cast(bf16x8, bfr[ks]), acc, 0, 0, 0);
    int p = nt * 16 + mc;
    int m0 = wvi * 16 + quad * 4;
    int a = m0 >> 3, b8 = m0 & 7;
    ushort4 pk;
    pk.x = f2bf(acc[0]); pk.y = f2bf(acc[1]);
    pk.z = f2bf(acc[2]); pk.w = f2bf(acc[3]);
    *reinterpret_cast<ushort4*>(yp + a * 256 + p * 8 + b8) = pk;
  }
}

// ---------------------------------------------------------------------------
// dwconv3 + exact GELU gate -> g bf16 (split g1[0:96) / g2[96:144)). LDS-free.
__global__ __launch_bounds__(256) void k_ffn_gate(
    const unsigned short* __restrict__ z, const float* __restrict__ dwf,
    unsigned short* __restrict__ g1, unsigned short* __restrict__ g2) {
  int tid = threadIdx.x;
  unsigned bid = blockIdx.x;
  int y0 = (int)(bid & 31) * 8;
  unsigned t = bid >> 5;
  int c = (int)(t % 144u);
  int b = (int)(t / 144u);
  const unsigned short* zp1 = z + ((size_t)(b * 288 + c)) * HWC;
  const unsigned short* zp2 = z + ((size_t)(b * 288 + 144 + c)) * HWC;
  float w1[9], w2[9];
#pragma unroll
  for (int k = 0; k < 9; k++) {
    w1[k] = dwf[c * 9 + k];
    w2[k] = dwf[(144 + c) * 9 + k];
  }
  int r = tid >> 5, seg = tid & 31, lane = tid & 63;
  int y = y0 + r;
  float f1[3][8], f2[3][8];
#pragma unroll
  for (int dy = 0; dy < 3; dy++) {
    int yy = y + dy - 1;
    if (yy >= 0 && yy < 256) {
      load8f(zp1 + yy * 256 + seg * 8, f1[dy]);
      load8f(zp2 + yy * 256 + seg * 8, f2[dy]);
    } else {
#pragma unroll
      for (int j = 0; j < 8; j++) { f1[dy][j] = 0.f; f2[dy][j] = 0.f; }
    }
  }
  float d1[8], d2[8];
#pragma unroll
  for (int j = 0; j < 8; j++) { d1[j] = 0.f; d2[j] = 0.f; }
#pragma unroll
  for (int dy = 0; dy < 3; dy++) {
    float lv1 = __shfl(f1[dy][7], lane - 1, 64);
    float rv1 = __shfl(f1[dy][0], lane + 1, 64);
    float lv2 = __shfl(f2[dy][7], lane - 1, 64);
    float rv2 = __shfl(f2[dy][0], lane + 1, 64);
    if (seg == 0) { lv1 = 0.f; lv2 = 0.f; }
    if (seg == 31) { rv1 = 0.f; rv2 = 0.f; }
#pragma unroll
    for (int j = 0; j < 8; j++) {
      float xl1 = (j == 0) ? lv1 : f1[dy][j - 1];
      float xr1 = (j == 7) ? rv1 : f1[dy][j + 1];
      float xl2 = (j == 0) ? lv2 : f2[dy][j - 1];
      float xr2 = (j == 7) ? rv2 : f2[dy][j + 1];
      d1[j] += xl1 * w1[dy * 3] + f1[dy][j] * w1[dy * 3 + 1] + xr1 * w1[dy * 3 + 2];
      d2[j] += xl2 * w2[dy * 3] + f2[dy][j] * w2[dy * 3 + 1] + xr2 * w2[dy * 3 + 2];
    }
  }
  float o[8];
#pragma unroll
  for (int j = 0; j < 8; j++)
    o[j] = 0.5f * d1[j] * (1.f + erff(d1[j] * 0.70710678118654752f)) * d2[j];
  unsigned short* gp = (c < 96)
      ? g1 + ((size_t)(b * 96 + c)) * HWC
      : g2 + ((size_t)(b * 48 + (c - 96))) * HWC;
  store8bf(gp + y * 256 + seg * 8, o);
}

// ---------------------------------------------------------------------------
extern "C" void kernel_launch(void* const* d_in, const int* in_sizes, int n_in,
                              void* d_out, int out_size, void* d_ws,
                              size_t ws_size, hipStream_t stream) {
  (void)in_sizes; (void)n_in; (void)out_size; (void)ws_size;
  const float* x   = (const float*)d_in[0];
  const float* n1w = (const float*)d_in[1];
  const float* n1b = (const float*)d_in[2];
  const float* awh = (const float*)d_in[3];   // [288,48]
  const float* adw = (const float*)d_in[4];   // [288,1,3,3]
  const float* anw = (const float*)d_in[5];   // [96]
  const float* anb = (const float*)d_in[6];
  const float* awo = (const float*)d_in[7];   // [48,96]
  const float* n2w = (const float*)d_in[8];
  const float* n2b = (const float*)d_in[9];
  const float* fwi = (const float*)d_in[10];  // [288,48]
  const float* fff = (const float*)d_in[11];  // [288,1,1,8,5]
  const float* fdw = (const float*)d_in[12];  // [288,1,3,3]
  const float* fwo = (const float*)d_in[13];  // [48,144]

  unsigned short* QKV  = (unsigned short*)d_ws;                       // 75.5 MB
  unsigned short* HID  = (unsigned short*)((char*)d_ws + 75497472);   // 75.5 MB
  unsigned short* U    = (unsigned short*)((char*)d_ws + 150994944);  // 25.2 MB
  unsigned short* X1   = (unsigned short*)((char*)d_ws + 176160768);  // 12.6 MB
  unsigned short* G2   = (unsigned short*)((char*)d_ws + 188743680);  // 12.6 MB
  unsigned short* CMAT = G2;  // 2.36 MB; dead before ffn_gate writes g2
  unsigned short* WP   = (unsigned short*)((char*)d_ws + 201326592);  // 96 KB
  unsigned short* WA = WP;             // awh padded [288][64]
  unsigned short* WO = WP + 18432;     // awo [48][96]
  unsigned short* WI = WP + 23040;     // fwi padded [288][64]
  unsigned short* WF = WP + 41472;     // fwo padded [48][160]

  k_prep_w<<<672, 64, 0, stream>>>(awh, awo, fwi, fwo, WP);
  k_make_cmat<<<288, 64, 0, stream>>>(fff, CMAT);
  // FSAS: hidden = W_h * LN1(x)  [LN fused]
  k_gemm<288, 48, 64, 1, 0><<<2048, 256, 0, stream>>>(WA, x, nullptr, n1w,
                                                      n1b, nullptr, HID);
  k_dwconv3v<<<2 * 96 * 32, 256, 0, stream>>>(HID, adw, QKV);      // v only
  k_fsas_fused<<<2 * 96 * 32, 256, 0, stream>>>(HID, adw, U);      // q,k fused
  // x1 = x + W_o * (LN(out96) * v)   [LN+gate fused in staging]
  k_gemm<48, 96, 96, 2, 1><<<2048, 256, 0, stream>>>(WO, U, QKV, anw, anb, x,
                                                     X1);
  // DFFN: y = W_in * LN(x1)  [LN fused]
  k_gemm<288, 48, 64, 3, 0><<<2048, 256, 0, stream>>>(WI, X1, nullptr, n2w,
                                                      n2b, nullptr, QKV);
  // z = C_c * y per patch (MFMA circulant), in-place
  k_patchconv_mfma<<<2 * 288 * 32, 256, 0, stream>>>(QKV, CMAT);
  k_ffn_gate<<<2 * 144 * 32, 256, 0, stream>>>(QKV, fdw, U, G2);
  // out = x1 + W_out * g  (g split U/G2), fp32 output
  k_gemm<48, 144, 160, 0, 2><<<2048, 256, 0, stream>>>(WF, U, G2, nullptr,
                                                       nullptr, X1,
                                                       (float*)d_out);
}

// Round 3
// 291.727 us; speedup vs baseline: 1.0945x; 1.0036x over previous
//
#include <hip/hip_runtime.h>
#include <hip/hip_bf16.h>
#include <cstddef>

// FFTformer block. FFTs reduced to 8x8 circular convolutions; conv1x1 GEMMs
// on MFMA (bf16 in, fp32 acc), LN/gate fused into GEMM staging, weights
// pre-converted to padded bf16 (A-frags from global), vectorized epilogue via
// LDS transpose (16B stores). FSAS dwconv(q,k) fused into the patchconv;
// patch conv done via per-row real DFT-8 (freq accumulate, 14 FMA/row-pair
// instead of 64). DFFN spectral filter = per-channel 64x64 circulant matmul
// on MFMA.  B=2, d=48, H=W=256, P=8.  Workspace (ws_size = 256 MiB):
//   [0,           75,497,472)  QKV bf16 [2,288,HW]  (v + later y -> z in-place)
//   [75,497,472, 150,994,944)  HID bf16 [2,288,HW]
//   [150,994,944,176,160,768)  U   bf16 [2,96,HW]   (out96/u -> g1)
//   [176,160,768,188,743,680)  X1  bf16 [2,48,HW]
//   [188,743,680,201,326,592)  G2  bf16 [2,48,HW]   (CMAT 2.36MB until ffn_gate)
//   [201,326,592,201,424,896)  WPAD bf16 (awh64 | awo96 | fwi64 | fwo160)

constexpr int HWC = 65536;   // 256*256

typedef short short8 __attribute__((ext_vector_type(8)));
typedef __bf16 bf16x8 __attribute__((ext_vector_type(8)));
typedef float f32x4 __attribute__((ext_vector_type(4)));

__device__ inline unsigned short f2bf(float f) {
  __hip_bfloat16 h = __float2bfloat16(f);
  return *reinterpret_cast<unsigned short*>(&h);
}
__device__ inline float bf2f(unsigned short u) {
  __hip_bfloat16 h;
  *reinterpret_cast<unsigned short*>(&h) = u;
  return __bfloat162float(h);
}

union V8 { uint4 v; unsigned short us[8]; short s[8]; };

__device__ inline void load8f(const unsigned short* p, float* f) {
  V8 u; u.v = *reinterpret_cast<const uint4*>(p);
#pragma unroll
  for (int j = 0; j < 8; j++) f[j] = bf2f(u.us[j]);
}
__device__ inline void store8bf(unsigned short* p, const float* f) {
  V8 u;
#pragma unroll
  for (int j = 0; j < 8; j++) u.us[j] = f2bf(f[j]);
  *reinterpret_cast<uint4*>(p) = u.v;
}

// Real DFT-8 of x[8] -> e = [X0, X1r, X1i, X2r, X2i, X3r, X3i, X4].
// Forward convention X[k] = sum x[n] e^{-2pi i k n / 8}.  ~24 VALU ops.
__device__ inline void fdft8(const float* x, float* e) {
  const float c = 0.70710678118654752f;
  float t0 = x[0] + x[4], t1 = x[0] - x[4];
  float t2 = x[2] + x[6], t3 = x[2] - x[6];
  float t4 = x[1] + x[5], t5 = x[1] - x[5];
  float t6 = x[3] + x[7], t7 = x[3] - x[7];
  float A = c * (t5 - t7), B = c * (t5 + t7);
  float s1 = t0 + t2, s2 = t4 + t6;
  e[0] = s1 + s2;        // X0
  e[7] = s1 - s2;        // X4
  e[1] = t1 + A;         // X1r
  e[5] = t1 - A;         // X3r
  e[2] = -(B + t3);      // X1i
  e[6] = t3 - B;         // X3i
  e[3] = t0 - t2;        // X2r
  e[4] = t6 - t4;        // X2i
}

// ---------------------------------------------------------------------------
// Pre-convert weights fp32 -> bf16, zero-padded rows (offsets in shorts):
// awh [288][48]->@0 [288][64]; awo [48][96]->@18432; fwi [288][48]->@23040
// [288][64]; fwo [48][144]->@41472 [48][160].
__global__ __launch_bounds__(64) void k_prep_w(
    const float* __restrict__ awh, const float* __restrict__ awo,
    const float* __restrict__ fwi, const float* __restrict__ fwo,
    unsigned short* __restrict__ wp) {
  int row = blockIdx.x, t = threadIdx.x;
  const float* src; int K, KP; unsigned short* dst;
  if (row < 288)      { src = awh + row * 48;        K = 48;  KP = 64;
                        dst = wp + row * 64; }
  else if (row < 336) { int r = row - 288; src = awo + r * 96; K = 96; KP = 96;
                        dst = wp + 18432 + r * 96; }
  else if (row < 624) { int r = row - 336; src = fwi + r * 48; K = 48; KP = 64;
                        dst = wp + 23040 + r * 64; }
  else                { int r = row - 624; src = fwo + r * 144; K = 144; KP = 160;
                        dst = wp + 41472 + r * 160; }
  for (int k = t; k < KP; k += 64) dst[k] = f2bf(k < K ? src[k] : 0.f);
}

// ---------------------------------------------------------------------------
// MFMA GEMM: out[M x N] = Wb[M x KP(bf16)] * X[K x N], 64 px/block.
// XF: 0 none (K split 96/48 s1/s2), 1 LN48 fp32 s1, 2 LN96+v-gate, 3 LN48 bf16.
// EPI: 0 write bf16[M]; 1 += fp32 res -> bf16 (M=48); 2 += bf16 res -> fp32.
// Epilogue: accs -> LDS (reuse Xs) -> cooperative 16B stores.
template <int M, int K, int KP, int XF, int EPI>
__global__ __launch_bounds__(256) void k_gemm(
    const unsigned short* __restrict__ wb, const void* __restrict__ s1,
    const unsigned short* __restrict__ s2, const float* __restrict__ lnw,
    const float* __restrict__ lnb, const void* __restrict__ res,
    void* __restrict__ out) {
  constexpr int STRIDE = KP + 8;
  constexpr int KS = KP / 32;
  constexpr int NT = (M + 63) / 64;
  __shared__ __align__(16) short Xs[64 * STRIDE];   // staging, then epilogue
  __shared__ __align__(16) short Vs[(XF == 2) ? 64 * STRIDE : 4];
  __shared__ float redS[4][64], redS2[4][64], mus[64], invs[64];

  int tid = threadIdx.x;
  unsigned bid = blockIdx.x;
  int b = (int)(bid >> 10);
  int hw0 = (int)(bid & 1023) * 64;

  // stage X transposed: Xs[col][k]
  if (XF == 1) {
    const float* xp = (const float*)s1 + (size_t)b * 48 * HWC + hw0;
    for (int idx = tid; idx < 48 * 16; idx += 256) {
      int c = idx >> 4, colg = (idx & 15) * 4;
      float4 f = *reinterpret_cast<const float4*>(xp + (size_t)c * HWC + colg);
      Xs[(colg + 0) * STRIDE + c] = (short)f2bf(f.x);
      Xs[(colg + 1) * STRIDE + c] = (short)f2bf(f.y);
      Xs[(colg + 2) * STRIDE + c] = (short)f2bf(f.z);
      Xs[(colg + 3) * STRIDE + c] = (short)f2bf(f.w);
    }
  } else if (XF == 2) {
    const unsigned short* up =
        (const unsigned short*)s1 + (size_t)b * 96 * HWC + hw0;
    const unsigned short* vp = s2 + ((size_t)(b * 288 + 192)) * HWC + hw0;
    for (int idx = tid; idx < 96 * 16; idx += 256) {
      int c = idx >> 4, colg = (idx & 15) * 4;
      ushort4 uv = *reinterpret_cast<const ushort4*>(up + (size_t)c * HWC + colg);
      Xs[(colg + 0) * STRIDE + c] = (short)uv.x;
      Xs[(colg + 1) * STRIDE + c] = (short)uv.y;
      Xs[(colg + 2) * STRIDE + c] = (short)uv.z;
      Xs[(colg + 3) * STRIDE + c] = (short)uv.w;
      ushort4 vv = *reinterpret_cast<const ushort4*>(vp + (size_t)c * HWC + colg);
      Vs[(colg + 0) * STRIDE + c] = (short)vv.x;
      Vs[(colg + 1) * STRIDE + c] = (short)vv.y;
      Vs[(colg + 2) * STRIDE + c] = (short)vv.z;
      Vs[(colg + 3) * STRIDE + c] = (short)vv.w;
    }
  } else if (XF == 3) {
    const unsigned short* xp =
        (const unsigned short*)s1 + (size_t)b * 48 * HWC + hw0;
    for (int idx = tid; idx < 48 * 16; idx += 256) {
      int c = idx >> 4, colg = (idx & 15) * 4;
      ushort4 uv = *reinterpret_cast<const ushort4*>(xp + (size_t)c * HWC + colg);
      Xs[(colg + 0) * STRIDE + c] = (short)uv.x;
      Xs[(colg + 1) * STRIDE + c] = (short)uv.y;
      Xs[(colg + 2) * STRIDE + c] = (short)uv.z;
      Xs[(colg + 3) * STRIDE + c] = (short)uv.w;
    }
  } else {
    const unsigned short* p1 =
        (const unsigned short*)s1 + (size_t)b * 96 * HWC + hw0;
    const unsigned short* p2 = s2 + (size_t)b * 48 * HWC + hw0;
    for (int idx = tid; idx < K * 16; idx += 256) {
      int c = idx >> 4, colg = (idx & 15) * 4;
      const unsigned short* p =
          (c < 96) ? (p1 + (size_t)c * HWC + colg)
                   : (p2 + (size_t)(c - 96) * HWC + colg);
      ushort4 uv = *reinterpret_cast<const ushort4*>(p);
      Xs[(colg + 0) * STRIDE + c] = (short)uv.x;
      Xs[(colg + 1) * STRIDE + c] = (short)uv.y;
      Xs[(colg + 2) * STRIDE + c] = (short)uv.z;
      Xs[(colg + 3) * STRIDE + c] = (short)uv.w;
    }
  }

  if constexpr (KP > K) {
    constexpr int PAD = KP - K;
    for (int idx = tid; idx < 64 * PAD; idx += 256) {
      int col = idx / PAD, c = K + (idx % PAD);
      Xs[col * STRIDE + c] = 0;
    }
  }

  if (XF != 0) {
    constexpr int KC = (XF == 2) ? 96 : 48;
    __syncthreads();
    {
      int col = tid & 63, q = tid >> 6;
      float s = 0.f, s2 = 0.f;
      for (int c = q * (KC / 4); c < (q + 1) * (KC / 4); c++) {
        float v = bf2f((unsigned short)Xs[col * STRIDE + c]);
        s += v; s2 += v * v;
      }
      redS[q][col] = s; redS2[q][col] = s2;
    }
    __syncthreads();
    if (tid < 64) {
      float ss = redS[0][tid] + redS[1][tid] + redS[2][tid] + redS[3][tid];
      float ss2 = redS2[0][tid] + redS2[1][tid] + redS2[2][tid] + redS2[3][tid];
      float mu = ss * (1.f / KC);
      float var = ss2 * (1.f / KC) - mu * mu;
      mus[tid] = mu; invs[tid] = rsqrtf(var + 1e-5f);
    }
    __syncthreads();
    for (int idx = tid; idx < KC * 64; idx += 256) {
      int c = idx >> 6, col = idx & 63;
      float v = bf2f((unsigned short)Xs[col * STRIDE + c]);
      v = (v - mus[col]) * invs[col] * lnw[c] + lnb[c];
      if (XF == 2) v *= bf2f((unsigned short)Vs[col * STRIDE + c]);
      Xs[col * STRIDE + c] = (short)f2bf(v);
    }
  }
  __syncthreads();

  int lane = tid & 63, wvi = tid >> 6;
  int quad = lane >> 4, mc = lane & 15;
  int kbase = quad * 8;

  // B fragments to registers (Xs free for epilogue reuse afterwards)
  short8 bfr[4][KS];
#pragma unroll
  for (int ns = 0; ns < 4; ns++)
#pragma unroll
    for (int ks = 0; ks < KS; ks++)
      bfr[ns][ks] = *reinterpret_cast<const short8*>(
          Xs + (ns * 16 + mc) * STRIDE + ks * 32 + kbase);

  short* Es = Xs;   // epilogue tile [64ch][72]
#pragma unroll
  for (int t = 0; t < NT; t++) {
    int mb = (wvi + 4 * t) * 16;
    f32x4 accs[4];
    if (mb < M) {
      short8 afr[KS];
#pragma unroll
      for (int ks = 0; ks < KS; ks++)
        afr[ks] = *reinterpret_cast<const short8*>(
            wb + (size_t)(mb + mc) * KP + ks * 32 + kbase);
#pragma unroll
      for (int ns = 0; ns < 4; ns++) {
        f32x4 acc = {0.f, 0.f, 0.f, 0.f};
#pragma unroll
        for (int ks = 0; ks < KS; ks++)
          acc = __builtin_amdgcn_mfma_f32_16x16x32_bf16(
              __builtin_bit_cast(bf16x8, afr[ks]),
              __builtin_bit_cast(bf16x8, bfr[ns][ks]), acc, 0, 0, 0);
        accs[ns] = acc;
      }
    }
    __syncthreads();   // Xs free / previous writeback done
    if (mb < M) {
      int chl = wvi * 16 + quad * 4;
#pragma unroll
      for (int ns = 0; ns < 4; ns++)
#pragma unroll
        for (int r = 0; r < 4; r++)
          Es[(chl + r) * 72 + ns * 16 + mc] = (short)f2bf(accs[ns][r]);
    }
    __syncthreads();
#pragma unroll
    for (int i = 0; i < 2; i++) {
      int chl = (tid >> 3) + 32 * i;
      int px0 = (tid & 7) * 8;
      int m = 64 * t + chl;
      if (m < M) {
        V8 ev;
        ev.v = *reinterpret_cast<const uint4*>(Es + chl * 72 + px0);
        size_t off = ((size_t)(b * ((EPI == 0) ? M : 48) + m)) * HWC + hw0 + px0;
        if (EPI == 0) {
          *reinterpret_cast<uint4*>((unsigned short*)out + off) = ev.v;
        } else if (EPI == 1) {
          const float* rp = (const float*)res + off;
          float4 ra = *reinterpret_cast<const float4*>(rp);
          float4 rb = *reinterpret_cast<const float4*>(rp + 4);
          V8 pk;
          pk.us[0] = f2bf(ra.x + bf2f(ev.us[0]));
          pk.us[1] = f2bf(ra.y + bf2f(ev.us[1]));
          pk.us[2] = f2bf(ra.z + bf2f(ev.us[2]));
          pk.us[3] = f2bf(ra.w + bf2f(ev.us[3]));
          pk.us[4] = f2bf(rb.x + bf2f(ev.us[4]));
          pk.us[5] = f2bf(rb.y + bf2f(ev.us[5]));
          pk.us[6] = f2bf(rb.z + bf2f(ev.us[6]));
          pk.us[7] = f2bf(rb.w + bf2f(ev.us[7]));
          *reinterpret_cast<uint4*>((unsigned short*)out + off) = pk.v;
        } else {
          V8 rv;
          rv.v = *reinterpret_cast<const uint4*>((const unsigned short*)res + off);
          float* op = (float*)out + off;
          float4 oa, ob;
          oa.x = bf2f(rv.us[0]) + bf2f(ev.us[0]);
          oa.y = bf2f(rv.us[1]) + bf2f(ev.us[1]);
          oa.z = bf2f(rv.us[2]) + bf2f(ev.us[2]);
          oa.w = bf2f(rv.us[3]) + bf2f(ev.us[3]);
          ob.x = bf2f(rv.us[4]) + bf2f(ev.us[4]);
          ob.y = bf2f(rv.us[5]) + bf2f(ev.us[5]);
          ob.z = bf2f(rv.us[6]) + bf2f(ev.us[6]);
          ob.w = bf2f(rv.us[7]) + bf2f(ev.us[7]);
          *reinterpret_cast<float4*>(op) = oa;
          *reinterpret_cast<float4*>(op + 4) = ob;
        }
      }
    }
  }
}

// ---------------------------------------------------------------------------
// depthwise 3x3 SAME for the 96 v-channels (192..287), LDS-free.
__global__ __launch_bounds__(256) void k_dwconv3v(
    const unsigned short* __restrict__ in, const float* __restrict__ dw,
    unsigned short* __restrict__ out) {
  int tid = threadIdx.x;
  unsigned bid = blockIdx.x;
  int y0 = (int)(bid & 31) * 8;
  unsigned t = bid >> 5;
  int c = 192 + (int)(t % 96u);
  int b = (int)(t / 96u);
  const unsigned short* ip = in + ((size_t)(b * 288 + c)) * HWC;
  float wv[9];
#pragma unroll
  for (int k = 0; k < 9; k++) wv[k] = dw[c * 9 + k];
  int r = tid >> 5, seg = tid & 31, lane = tid & 63;
  int y = y0 + r;
  float f[3][8];
#pragma unroll
  for (int dy = 0; dy < 3; dy++) {
    int yy = y + dy - 1;
    if (yy >= 0 && yy < 256) {
      load8f(ip + yy * 256 + seg * 8, f[dy]);
    } else {
#pragma unroll
      for (int j = 0; j < 8; j++) f[dy][j] = 0.f;
    }
  }
  float o[8];
#pragma unroll
  for (int dy = 0; dy < 3; dy++) {
    float lv = __shfl(f[dy][7], lane - 1, 64);
    float rv = __shfl(f[dy][0], lane + 1, 64);
    if (seg == 0) lv = 0.f;
    if (seg == 31) rv = 0.f;
#pragma unroll
    for (int j = 0; j < 8; j++) {
      float xl = (j == 0) ? lv : f[dy][j - 1];
      float xr = (j == 7) ? rv : f[dy][j + 1];
      float v = xl * wv[dy * 3] + f[dy][j] * wv[dy * 3 + 1] + xr * wv[dy * 3 + 2];
      o[j] = (dy == 0) ? v : o[j] + v;
    }
  }
  store8bf(out + ((size_t)(b * 288 + c)) * HWC + y * 256 + seg * 8, o);
}

// ---------------------------------------------------------------------------
// FSAS fused: dwconv3(hidden) for q,k computed on the fly (shuffle halo),
// then per-row real DFT-8 IN REGISTERS, freq rows staged to LDS (f32,
// LSTR=260).  Phase 2 accumulates the 2D circular conv in the row-frequency
// domain: per (i) row pair only 14 FMA (pointwise complex per bin) instead
// of 64; one inverse DFT-8 per output row at the end.  Same thread mapping
// and LDS traffic as the proven direct version; ~2.8x fewer phase-2 VALU ops.
__global__ __launch_bounds__(256) void k_fsas_fused(
    const unsigned short* __restrict__ hid, const float* __restrict__ dw,
    unsigned short* __restrict__ out) {
  constexpr int LSTR = 260;            // f32/row: 256 + 4 pad
  __shared__ __align__(16) float qs[8 * LSTR];
  __shared__ __align__(16) float kt[8 * LSTR];
  int tid = threadIdx.x;
  unsigned bid = blockIdx.x;                 // b*96*32 + c*32 + py
  int py = (int)(bid & 31);
  int c = (int)((bid >> 5) % 96u);
  int b = (int)((bid >> 5) / 96u);
  const unsigned short* qp = hid + ((size_t)(b * 288 + c)) * HWC;
  const unsigned short* kp = hid + ((size_t)(b * 288 + 96 + c)) * HWC;
  float w1[9], w2[9];
#pragma unroll
  for (int k = 0; k < 9; k++) {
    w1[k] = dw[c * 9 + k];
    w2[k] = dw[(96 + c) * 9 + k];
  }
  int r = tid >> 5, seg = tid & 31, lane = tid & 63;
  int y = py * 8 + r;
  float f1[3][8], f2[3][8];
#pragma unroll
  for (int dy = 0; dy < 3; dy++) {
    int yy = y + dy - 1;
    if (yy >= 0 && yy < 256) {
      load8f(qp + yy * 256 + seg * 8, f1[dy]);
      load8f(kp + yy * 256 + seg * 8, f2[dy]);
    } else {
#pragma unroll
      for (int j = 0; j < 8; j++) { f1[dy][j] = 0.f; f2[dy][j] = 0.f; }
    }
  }
  float d1[8], d2[8];
#pragma unroll
  for (int j = 0; j < 8; j++) { d1[j] = 0.f; d2[j] = 0.f; }
#pragma unroll
  for (int dy = 0; dy < 3; dy++) {
    float lv1 = __shfl(f1[dy][7], lane - 1, 64);
    float rv1 = __shfl(f1[dy][0], lane + 1, 64);
    float lv2 = __shfl(f2[dy][7], lane - 1, 64);
    float rv2 = __shfl(f2[dy][0], lane + 1, 64);
    if (seg == 0) { lv1 = 0.f; lv2 = 0.f; }
    if (seg == 31) { rv1 = 0.f; rv2 = 0.f; }
#pragma unroll
    for (int j = 0; j < 8; j++) {
      float xl1 = (j == 0) ? lv1 : f1[dy][j - 1];
      float xr1 = (j == 7) ? rv1 : f1[dy][j + 1];
      float xl2 = (j == 0) ? lv2 : f2[dy][j - 1];
      float xr2 = (j == 7) ? rv2 : f2[dy][j + 1];
      d1[j] += xl1 * w1[dy * 3] + f1[dy][j] * w1[dy * 3 + 1] + xr1 * w1[dy * 3 + 2];
      d2[j] += xl2 * w2[dy * 3] + f2[dy][j] * w2[dy * 3 + 1] + xr2 * w2[dy * 3 + 2];
    }
  }
  // per-row real DFT-8 in registers, store spectra
  {
    float e1[8], e2[8];
    fdft8(d1, e1);
    fdft8(d2, e2);
    float4 a1 = {e1[0], e1[1], e1[2], e1[3]};
    float4 b1 = {e1[4], e1[5], e1[6], e1[7]};
    float4 a2 = {e2[0], e2[1], e2[2], e2[3]};
    float4 b2 = {e2[4], e2[5], e2[6], e2[7]};
    *reinterpret_cast<float4*>(&qs[r * LSTR + seg * 8]) = a1;
    *reinterpret_cast<float4*>(&qs[r * LSTR + seg * 8 + 4]) = b1;
    *reinterpret_cast<float4*>(&kt[r * LSTR + seg * 8]) = a2;
    *reinterpret_cast<float4*>(&kt[r * LSTR + seg * 8 + 4]) = b2;
  }
  __syncthreads();
  // Phase 2: patch p = tid>>3 (col), output row a = tid&7.  Accumulate
  // Z[a][k] = sum_i Qhat[i][k] * Khat[(a-i)&7][k]  (complex per bin).
  int p = tid >> 3, a = tid & 7;
  float Z[8];
#pragma unroll
  for (int j = 0; j < 8; j++) Z[j] = 0.f;
#pragma unroll
  for (int i = 0; i < 8; i++) {
    float4 qa = *reinterpret_cast<const float4*>(&qs[i * LSTR + p * 8]);
    float4 qb = *reinterpret_cast<const float4*>(&qs[i * LSTR + p * 8 + 4]);
    int ar = (a - i) & 7;
    float4 ka = *reinterpret_cast<const float4*>(&kt[ar * LSTR + p * 8]);
    float4 kb = *reinterpret_cast<const float4*>(&kt[ar * LSTR + p * 8 + 4]);
    // bins: [X0, X1r, X1i, X2r, X2i, X3r, X3i, X4]
    Z[0] += qa.x * ka.x;                    // X0
    Z[7] += qb.w * kb.w;                    // X4
    Z[1] += qa.y * ka.y - qa.z * ka.z;      // X1r
    Z[2] += qa.y * ka.z + qa.z * ka.y;      // X1i
    Z[3] += qa.w * ka.w - qb.x * kb.x;      // X2r
    Z[4] += qa.w * kb.x + qb.x * ka.w;      // X2i
    Z[5] += qb.y * kb.y - qb.z * kb.z;      // X3r
    Z[6] += qb.y * kb.z + qb.z * kb.y;      // X3i
  }
  // inverse DFT-8 (z[n] = (1/8)[Z0 + (-1)^n Z4 + 2 sum_k Re(Zk e^{+i2pikn/8})])
  float acc[8];
  {
    const float c2 = 0.70710678118654752f;
    float Z0 = Z[0], Z1r = Z[1], Z1i = Z[2], Z2r = Z[3];
    float Z2i = Z[4], Z3r = Z[5], Z3i = Z[6], Z4 = Z[7];
    float u0 = Z0 + Z4, u1 = Z0 - Z4;
    float E = 2.f * Z2r, F = 2.f * (Z1r + Z3r), G = 2.f * (Z1i - Z3i);
    float T = 2.f * Z2i;
    float P = 2.f * c2 * (Z1r - Z1i), Qv = 2.f * c2 * (Z1r + Z1i);
    float R = 2.f * c2 * (Z3r + Z3i), S = 2.f * c2 * (Z3r - Z3i);
    acc[0] = 0.125f * (u0 + E + F);
    acc[4] = 0.125f * (u0 + E - F);
    acc[2] = 0.125f * (u0 - E - G);
    acc[6] = 0.125f * (u0 - E + G);
    acc[1] = 0.125f * (u1 + P - T - R);
    acc[3] = 0.125f * (u1 - Qv + T + S);
    acc[5] = 0.125f * (u1 - P - T + R);
    acc[7] = 0.125f * (u1 + Qv + T - S);
  }
  store8bf(out + ((size_t)(b * 96 + c)) * HWC + (py * 8 + a) * 256 + p * 8,
           acc);
}

// ---------------------------------------------------------------------------
// Cmat[c][m][k] (bf16): 64x64 circulant of s_c = irfft2(ffn_fft[c]) (numpy c2r
// semantics: v=0,4 columns symmetrized).
__device__ const float c_cos8[8] = {
    1.f, 0.70710678118654752f, 0.f, -0.70710678118654752f,
    -1.f, -0.70710678118654752f, 0.f, 0.70710678118654752f};

__global__ __launch_bounds__(64) void k_make_cmat(
    const float* __restrict__ fftw, unsigned short* __restrict__ cmat) {
  __shared__ float sf[64];
  int c = blockIdx.x;
  int a = threadIdx.x >> 3, b2 = threadIdx.x & 7;
  const float* W = fftw + c * 40;  // [8][5]
  float acc = 0.f;
  for (int u = 0; u < 8; u++) {
    for (int v = 0; v < 8; v++) {
      float wv;
      if (v <= 4) {
        if (v == 0 || v == 4)
          wv = 0.5f * (W[u * 5 + v] + W[((8 - u) & 7) * 5 + v]);
        else
          wv = W[u * 5 + v];
      } else {
        wv = W[((8 - u) & 7) * 5 + (8 - v)];
      }
      acc += wv * c_cos8[(u * a + v * b2) & 7];
    }
  }
  sf[threadIdx.x] = acc * (1.f / 64.f);
  __syncthreads();
  unsigned short* cp = cmat + (size_t)c * 4096 + threadIdx.x * 64;
  for (int k8 = 0; k8 < 64; k8 += 8) {
    float v[8];
    int ka = k8 >> 3;
    int ia = ((a - ka) & 7) * 8;
#pragma unroll
    for (int j = 0; j < 8; j++) v[j] = sf[ia + ((b2 - j) & 7)];
    store8bf(cp + k8, v);
  }
}

// ---------------------------------------------------------------------------
// DFFN spectral: z = C_c * y per patch, MFMA. IN-PLACE on y.
__global__ __launch_bounds__(256) void k_patchconv_mfma(
    unsigned short* y, const unsigned short* __restrict__ cmat) {
  __shared__ __align__(16) short Bs[32 * 72];
  __shared__ __align__(16) short As[64 * 72];
  int tid = threadIdx.x;
  unsigned bid = blockIdx.x;                 // b*288*32 + c*32 + py
  int py = (int)(bid & 31);
  int c = (int)((bid >> 5) % 288u);
  int b = (int)((bid >> 5) / 288u);
  unsigned short* yp = y + ((size_t)(b * 288 + c)) * HWC + py * 2048;
  {
    int rr = tid >> 5, seg = tid & 31;
    *reinterpret_cast<uint4*>(Bs + seg * 72 + rr * 8) =
        *reinterpret_cast<const uint4*>(yp + rr * 256 + seg * 8);
  }
  {
    const unsigned short* cp = cmat + (size_t)c * 4096;
    int m = tid >> 2, kq = (tid & 3) * 16;
    *reinterpret_cast<uint4*>(As + m * 72 + kq) =
        *reinterpret_cast<const uint4*>(cp + m * 64 + kq);
    *reinterpret_cast<uint4*>(As + m * 72 + kq + 8) =
        *reinterpret_cast<const uint4*>(cp + m * 64 + kq + 8);
  }
  __syncthreads();
  int lane = tid & 63, wvi = tid >> 6;
  int quad = lane >> 4, mc = lane & 15;
  int kbase = quad * 8;
  short8 afr[2];
#pragma unroll
  for (int ks = 0; ks < 2; ks++)
    afr[ks] = *reinterpret_cast<const short8*>(
        As + (wvi * 16 + mc) * 72 + ks * 32 + kbase);
#pragma unroll
  for (int nt = 0; nt < 2; nt++) {
    short8 bfr[2];
#pragma unroll
    for (int ks = 0; ks < 2; ks++)
      bfr[ks] = *reinterpret_cast<const short8*>(
          Bs + (nt * 16 + mc) * 72 + ks * 32 + kbase);
    f32x4 acc = {0.f, 0.f, 0.f, 0.f};
#pragma unroll
    for (int ks = 0; ks < 2; ks++)
      acc = __builtin_amdgcn_mfma_f32_16x16x32_bf16(
          __builtin_bit_cast(bf16x8, afr[ks]),
          __builtin_bit_cast(bf16x8, bfr[ks]), acc, 0, 0, 0);
    int p = nt * 16 + mc;
    int m0 = wvi * 16 + quad * 4;
    int a = m0 >> 3, b8 = m0 & 7;
    ushort4 pk;
    pk.x = f2bf(acc[0]); pk.y = f2bf(acc[1]);
    pk.z = f2bf(acc[2]); pk.w = f2bf(acc[3]);
    *reinterpret_cast<ushort4*>(yp + a * 256 + p * 8 + b8) = pk;
  }
}

// ---------------------------------------------------------------------------
// dwconv3 + exact GELU gate -> g bf16 (split g1[0:96) / g2[96:144)). LDS-free.
__global__ __launch_bounds__(256) void k_ffn_gate(
    const unsigned short* __restrict__ z, const float* __restrict__ dwf,
    unsigned short* __restrict__ g1, unsigned short* __restrict__ g2) {
  int tid = threadIdx.x;
  unsigned bid = blockIdx.x;
  int y0 = (int)(bid & 31) * 8;
  unsigned t = bid >> 5;
  int c = (int)(t % 144u);
  int b = (int)(t / 144u);
  const unsigned short* zp1 = z + ((size_t)(b * 288 + c)) * HWC;
  const unsigned short* zp2 = z + ((size_t)(b * 288 + 144 + c)) * HWC;
  float w1[9], w2[9];
#pragma unroll
  for (int k = 0; k < 9; k++) {
    w1[k] = dwf[c * 9 + k];
    w2[k] = dwf[(144 + c) * 9 + k];
  }
  int r = tid >> 5, seg = tid & 31, lane = tid & 63;
  int y = y0 + r;
  float f1[3][8], f2[3][8];
#pragma unroll
  for (int dy = 0; dy < 3; dy++) {
    int yy = y + dy - 1;
    if (yy >= 0 && yy < 256) {
      load8f(zp1 + yy * 256 + seg * 8, f1[dy]);
      load8f(zp2 + yy * 256 + seg * 8, f2[dy]);
    } else {
#pragma unroll
      for (int j = 0; j < 8; j++) { f1[dy][j] = 0.f; f2[dy][j] = 0.f; }
    }
  }
  float d1[8], d2[8];
#pragma unroll
  for (int j = 0; j < 8; j++) { d1[j] = 0.f; d2[j] = 0.f; }
#pragma unroll
  for (int dy = 0; dy < 3; dy++) {
    float lv1 = __shfl(f1[dy][7], lane - 1, 64);
    float rv1 = __shfl(f1[dy][0], lane + 1, 64);
    float lv2 = __shfl(f2[dy][7], lane - 1, 64);
    float rv2 = __shfl(f2[dy][0], lane + 1, 64);
    if (seg == 0) { lv1 = 0.f; lv2 = 0.f; }
    if (seg == 31) { rv1 = 0.f; rv2 = 0.f; }
#pragma unroll
    for (int j = 0; j < 8; j++) {
      float xl1 = (j == 0) ? lv1 : f1[dy][j - 1];
      float xr1 = (j == 7) ? rv1 : f1[dy][j + 1];
      float xl2 = (j == 0) ? lv2 : f2[dy][j - 1];
      float xr2 = (j == 7) ? rv2 : f2[dy][j + 1];
      d1[j] += xl1 * w1[dy * 3] + f1[dy][j] * w1[dy * 3 + 1] + xr1 * w1[dy * 3 + 2];
      d2[j] += xl2 * w2[dy * 3] + f2[dy][j] * w2[dy * 3 + 1] + xr2 * w2[dy * 3 + 2];
    }
  }
  float o[8];
#pragma unroll
  for (int j = 0; j < 8; j++)
    o[j] = 0.5f * d1[j] * (1.f + erff(d1[j] * 0.70710678118654752f)) * d2[j];
  unsigned short* gp = (c < 96)
      ? g1 + ((size_t)(b * 96 + c)) * HWC
      : g2 + ((size_t)(b * 48 + (c - 96))) * HWC;
  store8bf(gp + y * 256 + seg * 8, o);
}

// ---------------------------------------------------------------------------
extern "C" void kernel_launch(void* const* d_in, const int* in_sizes, int n_in,
                              void* d_out, int out_size, void* d_ws,
                              size_t ws_size, hipStream_t stream) {
  (void)in_sizes; (void)n_in; (void)out_size; (void)ws_size;
  const float* x   = (const float*)d_in[0];
  const float* n1w = (const float*)d_in[1];
  const float* n1b = (const float*)d_in[2];
  const float* awh = (const float*)d_in[3];   // [288,48]
  const float* adw = (const float*)d_in[4];   // [288,1,3,3]
  const float* anw = (const float*)d_in[5];   // [96]
  const float* anb = (const float*)d_in[6];
  const float* awo = (const float*)d_in[7];   // [48,96]
  const float* n2w = (const float*)d_in[8];
  const float* n2b = (const float*)d_in[9];
  const float* fwi = (const float*)d_in[10];  // [288,48]
  const float* fff = (const float*)d_in[11];  // [288,1,1,8,5]
  const float* fdw = (const float*)d_in[12];  // [288,1,3,3]
  const float* fwo = (const float*)d_in[13];  // [48,144]

  unsigned short* QKV  = (unsigned short*)d_ws;                       // 75.5 MB
  unsigned short* HID  = (unsigned short*)((char*)d_ws + 75497472);   // 75.5 MB
  unsigned short* U    = (unsigned short*)((char*)d_ws + 150994944);  // 25.2 MB
  unsigned short* X1   = (unsigned short*)((char*)d_ws + 176160768);  // 12.6 MB
  unsigned short* G2   = (unsigned short*)((char*)d_ws + 188743680);  // 12.6 MB
  unsigned short* CMAT = G2;  // 2.36 MB; dead before ffn_gate writes g2
  unsigned short* WP   = (unsigned short*)((char*)d_ws + 201326592);  // 96 KB
  unsigned short* WA = WP;             // awh padded [288][64]
  unsigned short* WO = WP + 18432;     // awo [48][96]
  unsigned short* WI = WP + 23040;     // fwi padded [288][64]
  unsigned short* WF = WP + 41472;     // fwo padded [48][160]

  k_prep_w<<<672, 64, 0, stream>>>(awh, awo, fwi, fwo, WP);
  k_make_cmat<<<288, 64, 0, stream>>>(fff, CMAT);
  // FSAS: hidden = W_h * LN1(x)  [LN fused]
  k_gemm<288, 48, 64, 1, 0><<<2048, 256, 0, stream>>>(WA, x, nullptr, n1w,
                                                      n1b, nullptr, HID);
  k_dwconv3v<<<2 * 96 * 32, 256, 0, stream>>>(HID, adw, QKV);      // v only
  k_fsas_fused<<<2 * 96 * 32, 256, 0, stream>>>(HID, adw, U);      // q,k fused
  // x1 = x + W_o * (LN(out96) * v)   [LN+gate fused in staging]
  k_gemm<48, 96, 96, 2, 1><<<2048, 256, 0, stream>>>(WO, U, QKV, anw, anb, x,
                                                     X1);
  // DFFN: y = W_in * LN(x1)  [LN fused]
  k_gemm<288, 48, 64, 3, 0><<<2048, 256, 0, stream>>>(WI, X1, nullptr, n2w,
                                                      n2b, nullptr, QKV);
  // z = C_c * y per patch (MFMA circulant), in-place
  k_patchconv_mfma<<<2 * 288 * 32, 256, 0, stream>>>(QKV, CMAT);
  k_ffn_gate<<<2 * 144 * 32, 256, 0, stream>>>(QKV, fdw, U, G2);
  // out = x1 + W_out * g  (g split U/G2), fp32 output
  k_gemm<48, 144, 160, 0, 2><<<2048, 256, 0, stream>>>(WF, U, G2, nullptr,
                                                       nullptr, X1,
                                                       (float*)d_out);
}